// Round 1
// baseline (1037.008 us; speedup 1.0000x reference)
//
#include <hip/hip_runtime.h>
#include <hip/hip_bf16.h>
#include <stdint.h>

#define T_TOK 8192
#define DDIM 1024
#define NEXP 8
#define IMOE 1024
#define ISH 4096
#define BK 64

typedef __attribute__((ext_vector_type(8))) short short8;
typedef __attribute__((ext_vector_type(8))) __bf16 bf16x8;
typedef __attribute__((ext_vector_type(4))) float floatx4;

// round-to-nearest-even fp32 -> bf16 bits
__device__ __forceinline__ unsigned short f2bf(float f) {
  union { float f; unsigned u; } v; v.f = f;
  unsigned r = v.u + 0x7fffu + ((v.u >> 16) & 1u);
  return (unsigned short)(r >> 16);
}

__device__ __forceinline__ floatx4 mfma16(short8 a, short8 b, floatx4 c) {
  return __builtin_amdgcn_mfma_f32_16x16x32_bf16(
      __builtin_bit_cast(bf16x8, a), __builtin_bit_cast(bf16x8, b), c, 0, 0, 0);
}

// async global->LDS, 16B per lane; LDS base must be wave-uniform
__device__ __forceinline__ void gload16(const void* g, void* l) {
  __builtin_amdgcn_global_load_lds((const __attribute__((address_space(1))) void*)g,
                                   (__attribute__((address_space(3))) void*)l, 16, 0, 0);
}

// ---------------- conversion kernels ----------------

__global__ void k_cast(const float* __restrict__ src, unsigned short* __restrict__ dst, int n) {
  int i = (blockIdx.x * blockDim.x + threadIdx.x) * 4;
  if (i < n) {
    float4 v = *(const float4*)(src + i);
    ushort4 o;
    o.x = f2bf(v.x); o.y = f2bf(v.y); o.z = f2bf(v.z); o.w = f2bf(v.w);
    *(ushort4*)(dst + i) = o;
  }
}

// src [batch][R][C] f32 -> dst [batch][C][R] bf16  (B^T layout for GEMM)
__global__ void k_transpose_cast(const float* __restrict__ src, unsigned short* __restrict__ dst,
                                 int R, int C) {
  __shared__ float tile[32][33];
  int b = blockIdx.z;
  int c0 = blockIdx.x * 32, r0 = blockIdx.y * 32;
  const float* s = src + (size_t)b * R * C;
  unsigned short* d = dst + (size_t)b * R * C;
  int tx = threadIdx.x, ty = threadIdx.y;  // 32 x 8
#pragma unroll
  for (int j = 0; j < 32; j += 8)
    tile[ty + j][tx] = s[(size_t)(r0 + ty + j) * C + c0 + tx];
  __syncthreads();
#pragma unroll
  for (int j = 0; j < 32; j += 8)
    d[(size_t)(c0 + ty + j) * R + r0 + tx] = f2bf(tile[tx][ty + j]);
}

// ---------------- router ----------------

__global__ void k_init(int* counts, int* cursor) {
  if (threadIdx.x < NEXP) { counts[threadIdx.x] = 0; cursor[threadIdx.x] = 0; }
}

__global__ void k_router(const float* __restrict__ x, const float* __restrict__ gw,
                         const float* __restrict__ sgw, float* __restrict__ logits_out,
                         int* __restrict__ topi, float* __restrict__ topw,
                         float* __restrict__ sgate, int* __restrict__ counts) {
  int wave = threadIdx.x >> 6;
  int lane = threadIdx.x & 63;
  int t = blockIdx.x * 4 + wave;
  const float* xr = x + (size_t)t * DDIM;
  float acc[9];
#pragma unroll
  for (int j = 0; j < 9; j++) acc[j] = 0.f;
  for (int d = lane; d < DDIM; d += 64) {
    float xv = xr[d];
    const float* g = gw + d * 8;
    float4 g0 = *(const float4*)g;
    float4 g1 = *(const float4*)(g + 4);
    acc[0] += xv * g0.x; acc[1] += xv * g0.y; acc[2] += xv * g0.z; acc[3] += xv * g0.w;
    acc[4] += xv * g1.x; acc[5] += xv * g1.y; acc[6] += xv * g1.z; acc[7] += xv * g1.w;
    acc[8] += xv * sgw[d];
  }
#pragma unroll
  for (int off = 32; off > 0; off >>= 1) {
#pragma unroll
    for (int j = 0; j < 9; j++) acc[j] += __shfl_xor(acc[j], off);
  }
  if (lane == 0) {
#pragma unroll
    for (int j = 0; j < 8; j++) logits_out[t * 8 + j] = acc[j];
    int i0 = 0;
#pragma unroll
    for (int j = 1; j < 8; j++) if (acc[j] > acc[i0]) i0 = j;
    int i1 = -1;
#pragma unroll
    for (int j = 0; j < 8; j++) {
      if (j == i0) continue;
      if (i1 < 0 || acc[j] > acc[i1]) i1 = j;
    }
    float e1 = expf(acc[i1] - acc[i0]);  // e0 = 1
    float inv = 1.f / (1.f + e1);
    topi[t * 2] = i0; topi[t * 2 + 1] = i1;
    topw[t * 2] = inv; topw[t * 2 + 1] = e1 * inv;
    sgate[t] = 1.f / (1.f + expf(-acc[8]));
    atomicAdd(&counts[i0], 1);
    atomicAdd(&counts[i1], 1);
  }
}

__global__ void k_offsets(const int* __restrict__ counts, int* __restrict__ seg_off) {
  if (threadIdx.x == 0) {
    int s = 0;
    for (int e = 0; e < NEXP; e++) { seg_off[e] = s; s += counts[e]; }
    seg_off[NEXP] = s;
  }
}

__global__ void k_scatter(const int* __restrict__ topi, const float* __restrict__ topw,
                          const int* __restrict__ seg_off, int* __restrict__ cursor,
                          int* __restrict__ ptok, float* __restrict__ pw) {
  int t = blockIdx.x * 256 + threadIdx.x;
  if (t >= T_TOK) return;
#pragma unroll
  for (int k = 0; k < 2; k++) {
    int e = topi[t * 2 + k];
    int pos = atomicAdd(&cursor[e], 1);
    int p = seg_off[e] + pos;
    ptok[p] = t;
    pw[p] = topw[t * 2 + k];
  }
}

// ---------------- GEMM kernels (MFMA bf16 16x16x32) ----------------
// Fused gate/up + SiLU, shared expert: C tile 128(M) x 64(N), dual-B accs.
__global__ __launch_bounds__(256, 2) void k_gu_shared(
    const unsigned short* __restrict__ Xb,   // [8192][1024]
    const unsigned short* __restrict__ BgT,  // [4096][1024]
    const unsigned short* __restrict__ BuT,  // [4096][1024]
    unsigned short* __restrict__ H)          // [8192][4096]
{
  __shared__ __align__(16) unsigned short As[128 * BK];
  __shared__ __align__(16) unsigned short Bgs[64 * BK];
  __shared__ __align__(16) unsigned short Bus[64 * BK];

  const int tm0 = blockIdx.x * 128;
  const int tn0 = blockIdx.y * 64;
  const int tid = threadIdx.x;
  const int wave = tid >> 6, lane = tid & 63;
  const int wm = wave & 1, wn = wave >> 1;
  const int quad = lane >> 4, l16 = lane & 15;
  const int srow = lane >> 3;        // 8 lanes per 64-elem row
  const int scol = (lane & 7) * 8;

  floatx4 accg[4][2] = {};
  floatx4 accu[4][2] = {};

  for (int k0 = 0; k0 < DDIM; k0 += BK) {
#pragma unroll
    for (int s = 0; s < 4; s++) {
      int rb = (wave * 4 + s) * 8;
      gload16(Xb + (size_t)(tm0 + rb + srow) * DDIM + k0 + scol, As + rb * BK);
    }
#pragma unroll
    for (int s = 0; s < 2; s++) {
      int rb = (wave * 2 + s) * 8;
      gload16(BgT + (size_t)(tn0 + rb + srow) * DDIM + k0 + scol, Bgs + rb * BK);
      gload16(BuT + (size_t)(tn0 + rb + srow) * DDIM + k0 + scol, Bus + rb * BK);
    }
    __syncthreads();
#pragma unroll
    for (int ks = 0; ks < BK; ks += 32) {
      short8 af[4], bg[2], bu[2];
#pragma unroll
      for (int f = 0; f < 4; f++)
        af[f] = *(const short8*)(As + (wm * 64 + f * 16 + l16) * BK + ks + quad * 8);
#pragma unroll
      for (int f = 0; f < 2; f++) {
        bg[f] = *(const short8*)(Bgs + (wn * 32 + f * 16 + l16) * BK + ks + quad * 8);
        bu[f] = *(const short8*)(Bus + (wn * 32 + f * 16 + l16) * BK + ks + quad * 8);
      }
#pragma unroll
      for (int fm = 0; fm < 4; fm++)
#pragma unroll
        for (int fn = 0; fn < 2; fn++) {
          accg[fm][fn] = mfma16(af[fm], bg[fn], accg[fm][fn]);
          accu[fm][fn] = mfma16(af[fm], bu[fn], accu[fm][fn]);
        }
    }
    __syncthreads();
  }
#pragma unroll
  for (int fm = 0; fm < 4; fm++)
#pragma unroll
    for (int reg = 0; reg < 4; reg++) {
      int r = tm0 + wm * 64 + fm * 16 + quad * 4 + reg;
#pragma unroll
      for (int fn = 0; fn < 2; fn++) {
        int c = tn0 + wn * 32 + fn * 16 + l16;
        float g = accg[fm][fn][reg];
        float u = accu[fm][fn][reg];
        float h = (g / (1.f + __expf(-g))) * u;
        H[(size_t)r * ISH + c] = f2bf(h);
      }
    }
}

// Fused gate/up + SiLU for routed experts (gathered A rows).
__global__ __launch_bounds__(256, 2) void k_gu_expert(
    const unsigned short* __restrict__ Xb,
    const unsigned short* __restrict__ EgT,  // [E][1024][1024]
    const unsigned short* __restrict__ EuT,
    const int* __restrict__ seg_off,
    const int* __restrict__ ptok,
    unsigned short* __restrict__ Hp)         // [16384][1024] by pair slot
{
  const int e = blockIdx.x >> 6;
  const int mt = blockIdx.x & 63;
  const int s0 = seg_off[e];
  const int cnt = seg_off[e + 1] - s0;
  const int tm0 = mt * 128;
  if (tm0 >= cnt) return;

  __shared__ __align__(16) unsigned short As[128 * BK];
  __shared__ __align__(16) unsigned short Bgs[64 * BK];
  __shared__ __align__(16) unsigned short Bus[64 * BK];

  const int tn0 = blockIdx.y * 64;
  const int tid = threadIdx.x;
  const int wave = tid >> 6, lane = tid & 63;
  const int wm = wave & 1, wn = wave >> 1;
  const int quad = lane >> 4, l16 = lane & 15;
  const int srow = lane >> 3;
  const int scol = (lane & 7) * 8;

  const unsigned short* Bg = EgT + (size_t)e * IMOE * DDIM;
  const unsigned short* Bu = EuT + (size_t)e * IMOE * DDIM;

  int tokr[4];
#pragma unroll
  for (int s = 0; s < 4; s++) {
    int row = tm0 + (wave * 4 + s) * 8 + srow;
    tokr[s] = ptok[s0 + min(row, cnt - 1)];
  }

  floatx4 accg[4][2] = {};
  floatx4 accu[4][2] = {};

  for (int k0 = 0; k0 < DDIM; k0 += BK) {
#pragma unroll
    for (int s = 0; s < 4; s++) {
      int rb = (wave * 4 + s) * 8;
      gload16(Xb + (size_t)tokr[s] * DDIM + k0 + scol, As + rb * BK);
    }
#pragma unroll
    for (int s = 0; s < 2; s++) {
      int rb = (wave * 2 + s) * 8;
      gload16(Bg + (size_t)(tn0 + rb + srow) * DDIM + k0 + scol, Bgs + rb * BK);
      gload16(Bu + (size_t)(tn0 + rb + srow) * DDIM + k0 + scol, Bus + rb * BK);
    }
    __syncthreads();
#pragma unroll
    for (int ks = 0; ks < BK; ks += 32) {
      short8 af[4], bg[2], bu[2];
#pragma unroll
      for (int f = 0; f < 4; f++)
        af[f] = *(const short8*)(As + (wm * 64 + f * 16 + l16) * BK + ks + quad * 8);
#pragma unroll
      for (int f = 0; f < 2; f++) {
        bg[f] = *(const short8*)(Bgs + (wn * 32 + f * 16 + l16) * BK + ks + quad * 8);
        bu[f] = *(const short8*)(Bus + (wn * 32 + f * 16 + l16) * BK + ks + quad * 8);
      }
#pragma unroll
      for (int fm = 0; fm < 4; fm++)
#pragma unroll
        for (int fn = 0; fn < 2; fn++) {
          accg[fm][fn] = mfma16(af[fm], bg[fn], accg[fm][fn]);
          accu[fm][fn] = mfma16(af[fm], bu[fn], accu[fm][fn]);
        }
    }
    __syncthreads();
  }
#pragma unroll
  for (int fm = 0; fm < 4; fm++)
#pragma unroll
    for (int reg = 0; reg < 4; reg++) {
      int rloc = tm0 + wm * 64 + fm * 16 + quad * 4 + reg;
      if (rloc < cnt) {
#pragma unroll
        for (int fn = 0; fn < 2; fn++) {
          int c = tn0 + wn * 32 + fn * 16 + l16;
          float g = accg[fm][fn][reg];
          float u = accu[fm][fn][reg];
          Hp[(size_t)(s0 + rloc) * IMOE + c] = f2bf((g / (1.f + __expf(-g))) * u);
        }
      }
    }
}

// Shared-expert down proj: out = sigmoid_gate[t] * (Hsh @ sd). Writes full out.
__global__ __launch_bounds__(256, 2) void k_down_shared(
    const unsigned short* __restrict__ Hsh,  // [8192][4096]
    const unsigned short* __restrict__ SdT,  // [1024][4096]
    const float* __restrict__ sgate,
    float* __restrict__ out)                 // [8192][1024]
{
  __shared__ __align__(16) unsigned short As[128 * BK];
  __shared__ __align__(16) unsigned short Bs[128 * BK];

  const int tm0 = blockIdx.x * 128;
  const int tn0 = blockIdx.y * 128;
  const int tid = threadIdx.x;
  const int wave = tid >> 6, lane = tid & 63;
  const int wm = wave & 1, wn = wave >> 1;
  const int quad = lane >> 4, l16 = lane & 15;
  const int srow = lane >> 3;
  const int scol = (lane & 7) * 8;

  floatx4 acc[4][4] = {};

  for (int k0 = 0; k0 < ISH; k0 += BK) {
#pragma unroll
    for (int s = 0; s < 4; s++) {
      int rb = (wave * 4 + s) * 8;
      gload16(Hsh + (size_t)(tm0 + rb + srow) * ISH + k0 + scol, As + rb * BK);
      gload16(SdT + (size_t)(tn0 + rb + srow) * ISH + k0 + scol, Bs + rb * BK);
    }
    __syncthreads();
#pragma unroll
    for (int ks = 0; ks < BK; ks += 32) {
      short8 af[4], bfr[4];
#pragma unroll
      for (int f = 0; f < 4; f++) {
        af[f] = *(const short8*)(As + (wm * 64 + f * 16 + l16) * BK + ks + quad * 8);
        bfr[f] = *(const short8*)(Bs + (wn * 64 + f * 16 + l16) * BK + ks + quad * 8);
      }
#pragma unroll
      for (int fm = 0; fm < 4; fm++)
#pragma unroll
        for (int fn = 0; fn < 4; fn++)
          acc[fm][fn] = mfma16(af[fm], bfr[fn], acc[fm][fn]);
    }
    __syncthreads();
  }
#pragma unroll
  for (int fm = 0; fm < 4; fm++)
#pragma unroll
    for (int reg = 0; reg < 4; reg++) {
      int r = tm0 + wm * 64 + fm * 16 + quad * 4 + reg;
      float gt = sgate[r];
#pragma unroll
      for (int fn = 0; fn < 4; fn++) {
        int c = tn0 + wn * 64 + fn * 16 + l16;
        out[(size_t)r * DDIM + c] = gt * acc[fm][fn][reg];
      }
    }
}

// Expert down proj: out[tok] += w_pair * (Hp @ ed[e]) via atomics.
__global__ __launch_bounds__(256, 2) void k_down_expert(
    const unsigned short* __restrict__ Hp,   // [16384][1024]
    const unsigned short* __restrict__ EdT,  // [E][1024][1024]
    const int* __restrict__ seg_off,
    const int* __restrict__ ptok,
    const float* __restrict__ pw,
    float* __restrict__ out)
{
  const int e = blockIdx.x >> 6;
  const int mt = blockIdx.x & 63;
  const int s0 = seg_off[e];
  const int cnt = seg_off[e + 1] - s0;
  const int tm0 = mt * 128;
  if (tm0 >= cnt) return;

  __shared__ __align__(16) unsigned short As[128 * BK];
  __shared__ __align__(16) unsigned short Bs[128 * BK];

  const int tn0 = blockIdx.y * 128;
  const int tid = threadIdx.x;
  const int wave = tid >> 6, lane = tid & 63;
  const int wm = wave & 1, wn = wave >> 1;
  const int quad = lane >> 4, l16 = lane & 15;
  const int srow = lane >> 3;
  const int scol = (lane & 7) * 8;

  const unsigned short* B = EdT + (size_t)e * IMOE * DDIM;

  floatx4 acc[4][4] = {};

  for (int k0 = 0; k0 < IMOE; k0 += BK) {
#pragma unroll
    for (int s = 0; s < 4; s++) {
      int rb = (wave * 4 + s) * 8;
      int rowg = s0 + min(tm0 + rb + srow, cnt - 1);
      gload16(Hp + (size_t)rowg * IMOE + k0 + scol, As + rb * BK);
      gload16(B + (size_t)(tn0 + rb + srow) * IMOE + k0 + scol, Bs + rb * BK);
    }
    __syncthreads();
#pragma unroll
    for (int ks = 0; ks < BK; ks += 32) {
      short8 af[4], bfr[4];
#pragma unroll
      for (int f = 0; f < 4; f++) {
        af[f] = *(const short8*)(As + (wm * 64 + f * 16 + l16) * BK + ks + quad * 8);
        bfr[f] = *(const short8*)(Bs + (wn * 64 + f * 16 + l16) * BK + ks + quad * 8);
      }
#pragma unroll
      for (int fm = 0; fm < 4; fm++)
#pragma unroll
        for (int fn = 0; fn < 4; fn++)
          acc[fm][fn] = mfma16(af[fm], bfr[fn], acc[fm][fn]);
    }
    __syncthreads();
  }
#pragma unroll
  for (int fm = 0; fm < 4; fm++)
#pragma unroll
    for (int reg = 0; reg < 4; reg++) {
      int rloc = tm0 + wm * 64 + fm * 16 + quad * 4 + reg;
      if (rloc < cnt) {
        int p = s0 + rloc;
        int t = ptok[p];
        float w = pw[p];
#pragma unroll
        for (int fn = 0; fn < 4; fn++) {
          int c = tn0 + wn * 64 + fn * 16 + l16;
          atomicAdd(&out[(size_t)t * DDIM + c], w * acc[fm][fn][reg]);
        }
      }
    }
}

// ---------------- launch ----------------

extern "C" void kernel_launch(void* const* d_in, const int* in_sizes, int n_in,
                              void* d_out, int out_size, void* d_ws, size_t ws_size,
                              hipStream_t stream) {
  const float* x   = (const float*)d_in[0];
  const float* gw  = (const float*)d_in[1];
  const float* eg  = (const float*)d_in[2];
  const float* eu  = (const float*)d_in[3];
  const float* ed  = (const float*)d_in[4];
  const float* sg  = (const float*)d_in[5];
  const float* su  = (const float*)d_in[6];
  const float* sd  = (const float*)d_in[7];
  const float* sgw = (const float*)d_in[8];

  float* out    = (float*)d_out;                 // [8192][1024]
  float* logits = out + (size_t)T_TOK * DDIM;    // [8192][8]

  char* ws = (char*)d_ws;
  unsigned short* xb   = (unsigned short*)(ws + 0);            // 16 MB
  unsigned short* egT  = (unsigned short*)(ws + 16777216);     // 16 MB
  unsigned short* euT  = (unsigned short*)(ws + 33554432);     // 16 MB
  unsigned short* edT  = (unsigned short*)(ws + 50331648);     // 16 MB
  unsigned short* sgT  = (unsigned short*)(ws + 67108864);     // 8 MB
  unsigned short* suT  = (unsigned short*)(ws + 75497472);     // 8 MB
  unsigned short* sdT  = (unsigned short*)(ws + 83886080);     // 8 MB
  unsigned short* hsh  = (unsigned short*)(ws + 92274688);     // 64 MB
  unsigned short* hp   = (unsigned short*)(ws + 159383552);    // 32 MB
  int*   topi    = (int*)  (ws + 192937984);
  float* topw    = (float*)(ws + 193003520);
  float* sgate   = (float*)(ws + 193069056);
  int*   ptok    = (int*)  (ws + 193101824);
  float* pw      = (float*)(ws + 193167360);
  int*   counts  = (int*)  (ws + 193232896);
  int*   cursor  = (int*)  (ws + 193232960);
  int*   seg_off = (int*)  (ws + 193233024);

  k_init<<<1, 64, 0, stream>>>(counts, cursor);
  k_cast<<<8192, 256, 0, stream>>>(x, xb, T_TOK * DDIM);
  k_transpose_cast<<<dim3(32, 32, 8), dim3(32, 8), 0, stream>>>(eg, egT, DDIM, IMOE);
  k_transpose_cast<<<dim3(32, 32, 8), dim3(32, 8), 0, stream>>>(eu, euT, DDIM, IMOE);
  k_transpose_cast<<<dim3(32, 32, 8), dim3(32, 8), 0, stream>>>(ed, edT, IMOE, DDIM);
  k_transpose_cast<<<dim3(128, 32, 1), dim3(32, 8), 0, stream>>>(sg, sgT, DDIM, ISH);
  k_transpose_cast<<<dim3(128, 32, 1), dim3(32, 8), 0, stream>>>(su, suT, DDIM, ISH);
  k_transpose_cast<<<dim3(32, 128, 1), dim3(32, 8), 0, stream>>>(sd, sdT, ISH, DDIM);

  k_router<<<T_TOK / 4, 256, 0, stream>>>(x, gw, sgw, logits, topi, topw, sgate, counts);
  k_offsets<<<1, 64, 0, stream>>>(counts, seg_off);
  k_scatter<<<T_TOK / 256, 256, 0, stream>>>(topi, topw, seg_off, cursor, ptok, pw);

  k_gu_shared<<<dim3(64, 64), 256, 0, stream>>>(xb, sgT, suT, hsh);
  k_gu_expert<<<dim3(512, 16), 256, 0, stream>>>(xb, egT, euT, seg_off, ptok, hp);
  k_down_shared<<<dim3(64, 8), 256, 0, stream>>>(hsh, sdT, sgate, out);
  k_down_expert<<<dim3(512, 8), 256, 0, stream>>>(hp, edT, seg_off, ptok, pw, out);

  (void)in_sizes; (void)n_in; (void)out_size; (void)ws_size;
}

// Round 2
// 835.329 us; speedup vs baseline: 1.2414x; 1.2414x over previous
//
#include <hip/hip_runtime.h>
#include <hip/hip_bf16.h>
#include <stdint.h>

#define T_TOK 8192
#define DDIM 1024
#define NEXP 8
#define IMOE 1024
#define ISH 4096
#define BK 64

typedef __attribute__((ext_vector_type(8))) short short8;
typedef __attribute__((ext_vector_type(8))) __bf16 bf16x8;
typedef __attribute__((ext_vector_type(4))) float floatx4;

// round-to-nearest-even fp32 -> bf16 bits
__device__ __forceinline__ unsigned short f2bf(float f) {
  union { float f; unsigned u; } v; v.f = f;
  unsigned r = v.u + 0x7fffu + ((v.u >> 16) & 1u);
  return (unsigned short)(r >> 16);
}

__device__ __forceinline__ floatx4 mfma16(short8 a, short8 b, floatx4 c) {
  return __builtin_amdgcn_mfma_f32_16x16x32_bf16(
      __builtin_bit_cast(bf16x8, a), __builtin_bit_cast(bf16x8, b), c, 0, 0, 0);
}

// async global->LDS, 16B per lane; LDS base must be wave-uniform
__device__ __forceinline__ void gload16(const void* g, void* l) {
  __builtin_amdgcn_global_load_lds((const __attribute__((address_space(1))) void*)g,
                                   (__attribute__((address_space(3))) void*)l, 16, 0, 0);
}

// ---------------- conversion kernels ----------------

__global__ void k_cast(const float* __restrict__ src, unsigned short* __restrict__ dst, int n) {
  int i = (blockIdx.x * blockDim.x + threadIdx.x) * 4;
  if (i < n) {
    float4 v = *(const float4*)(src + i);
    ushort4 o;
    o.x = f2bf(v.x); o.y = f2bf(v.y); o.z = f2bf(v.z); o.w = f2bf(v.w);
    *(ushort4*)(dst + i) = o;
  }
}

// src [batch][R][C] f32 -> dst [batch][C][R] bf16  (B^T layout for GEMM)
__global__ void k_transpose_cast(const float* __restrict__ src, unsigned short* __restrict__ dst,
                                 int R, int C) {
  __shared__ float tile[32][33];
  int b = blockIdx.z;
  int c0 = blockIdx.x * 32, r0 = blockIdx.y * 32;
  const float* s = src + (size_t)b * R * C;
  unsigned short* d = dst + (size_t)b * R * C;
  int tx = threadIdx.x, ty = threadIdx.y;  // 32 x 8
#pragma unroll
  for (int j = 0; j < 32; j += 8)
    tile[ty + j][tx] = s[(size_t)(r0 + ty + j) * C + c0 + tx];
  __syncthreads();
#pragma unroll
  for (int j = 0; j < 32; j += 8)
    d[(size_t)(c0 + ty + j) * R + r0 + tx] = f2bf(tile[tx][ty + j]);
}

// ---------------- router (no global atomics) ----------------

__global__ void k_router(const float* __restrict__ x, const float* __restrict__ gw,
                         const float* __restrict__ sgw, float* __restrict__ logits_out,
                         int* __restrict__ topi, float* __restrict__ topw,
                         float* __restrict__ sgate) {
  int wave = threadIdx.x >> 6;
  int lane = threadIdx.x & 63;
  int t = blockIdx.x * 4 + wave;
  const float* xr = x + (size_t)t * DDIM;
  float acc[9];
#pragma unroll
  for (int j = 0; j < 9; j++) acc[j] = 0.f;
  for (int d = lane; d < DDIM; d += 64) {
    float xv = xr[d];
    const float* g = gw + d * 8;
    float4 g0 = *(const float4*)g;
    float4 g1 = *(const float4*)(g + 4);
    acc[0] += xv * g0.x; acc[1] += xv * g0.y; acc[2] += xv * g0.z; acc[3] += xv * g0.w;
    acc[4] += xv * g1.x; acc[5] += xv * g1.y; acc[6] += xv * g1.z; acc[7] += xv * g1.w;
    acc[8] += xv * sgw[d];
  }
#pragma unroll
  for (int off = 32; off > 0; off >>= 1) {
#pragma unroll
    for (int j = 0; j < 9; j++) acc[j] += __shfl_xor(acc[j], off);
  }
  if (lane == 0) {
#pragma unroll
    for (int j = 0; j < 8; j++) logits_out[t * 8 + j] = acc[j];
    int i0 = 0;
#pragma unroll
    for (int j = 1; j < 8; j++) if (acc[j] > acc[i0]) i0 = j;
    int i1 = -1;
#pragma unroll
    for (int j = 0; j < 8; j++) {
      if (j == i0) continue;
      if (i1 < 0 || acc[j] > acc[i1]) i1 = j;
    }
    float e1 = expf(acc[i1] - acc[i0]);  // e0 = 1
    float inv = 1.f / (1.f + e1);
    topi[t * 2] = i0; topi[t * 2 + 1] = i1;
    topw[t * 2] = inv; topw[t * 2 + 1] = e1 * inv;
    sgate[t] = 1.f / (1.f + expf(-acc[8]));
  }
}

// Counting sort pass 1: per-block expert histogram (LDS atomics only).
__global__ void k_hist(const int* __restrict__ topi, int* __restrict__ blockhist) {
  __shared__ int h[NEXP];
  if (threadIdx.x < NEXP) h[threadIdx.x] = 0;
  __syncthreads();
  int i = blockIdx.x * 256 + threadIdx.x;  // pair index
  atomicAdd(&h[topi[i]], 1);
  __syncthreads();
  if (threadIdx.x < NEXP) blockhist[blockIdx.x * NEXP + threadIdx.x] = h[threadIdx.x];
}

// Pass 2: per-(block,expert) base offsets + expert segment offsets. Tiny.
__global__ void k_offsets(const int* __restrict__ blockhist, int* __restrict__ seg_off,
                          int* __restrict__ blockbase) {
  if (threadIdx.x == 0) {
    int tot[NEXP];
#pragma unroll
    for (int e = 0; e < NEXP; e++) tot[e] = 0;
    for (int b = 0; b < 64; b++)
      for (int e = 0; e < NEXP; e++) {
        blockbase[b * NEXP + e] = tot[e];
        tot[e] += blockhist[b * NEXP + e];
      }
    int s = 0;
    for (int e = 0; e < NEXP; e++) { seg_off[e] = s; s += tot[e]; }
    seg_off[NEXP] = s;
    for (int b = 0; b < 64; b++)
      for (int e = 0; e < NEXP; e++) blockbase[b * NEXP + e] += seg_off[e];
  }
}

// Pass 3: scatter with per-block LDS cursors (no global atomics).
__global__ void k_scatter(const int* __restrict__ topi, const float* __restrict__ topw,
                          const int* __restrict__ blockbase,
                          int* __restrict__ ptok, float* __restrict__ pw) {
  __shared__ int cur[NEXP];
  if (threadIdx.x < NEXP) cur[threadIdx.x] = blockbase[blockIdx.x * NEXP + threadIdx.x];
  __syncthreads();
  int i = blockIdx.x * 256 + threadIdx.x;  // pair index
  int e = topi[i];
  int pos = atomicAdd(&cur[e], 1);
  ptok[pos] = i >> 1;
  pw[pos] = topw[i];
}

// ---------------- GEMM kernels (MFMA bf16 16x16x32) ----------------
// Fused gate/up + SiLU, shared expert: C tile 128(M) x 64(N), dual-B accs.
__global__ __launch_bounds__(256, 2) void k_gu_shared(
    const unsigned short* __restrict__ Xb,   // [8192][1024]
    const unsigned short* __restrict__ BgT,  // [4096][1024]
    const unsigned short* __restrict__ BuT,  // [4096][1024]
    unsigned short* __restrict__ H)          // [8192][4096]
{
  __shared__ __align__(16) unsigned short As[128 * BK];
  __shared__ __align__(16) unsigned short Bgs[64 * BK];
  __shared__ __align__(16) unsigned short Bus[64 * BK];

  const int tm0 = blockIdx.x * 128;
  const int tn0 = blockIdx.y * 64;
  const int tid = threadIdx.x;
  const int wave = tid >> 6, lane = tid & 63;
  const int wm = wave & 1, wn = wave >> 1;
  const int quad = lane >> 4, l16 = lane & 15;
  const int srow = lane >> 3;        // 8 lanes per 64-elem row
  const int scol = (lane & 7) * 8;

  floatx4 accg[4][2] = {};
  floatx4 accu[4][2] = {};

  for (int k0 = 0; k0 < DDIM; k0 += BK) {
#pragma unroll
    for (int s = 0; s < 4; s++) {
      int rb = (wave * 4 + s) * 8;
      gload16(Xb + (size_t)(tm0 + rb + srow) * DDIM + k0 + scol, As + rb * BK);
    }
#pragma unroll
    for (int s = 0; s < 2; s++) {
      int rb = (wave * 2 + s) * 8;
      gload16(BgT + (size_t)(tn0 + rb + srow) * DDIM + k0 + scol, Bgs + rb * BK);
      gload16(BuT + (size_t)(tn0 + rb + srow) * DDIM + k0 + scol, Bus + rb * BK);
    }
    __syncthreads();
#pragma unroll
    for (int ks = 0; ks < BK; ks += 32) {
      short8 af[4], bg[2], bu[2];
#pragma unroll
      for (int f = 0; f < 4; f++)
        af[f] = *(const short8*)(As + (wm * 64 + f * 16 + l16) * BK + ks + quad * 8);
#pragma unroll
      for (int f = 0; f < 2; f++) {
        bg[f] = *(const short8*)(Bgs + (wn * 32 + f * 16 + l16) * BK + ks + quad * 8);
        bu[f] = *(const short8*)(Bus + (wn * 32 + f * 16 + l16) * BK + ks + quad * 8);
      }
#pragma unroll
      for (int fm = 0; fm < 4; fm++)
#pragma unroll
        for (int fn = 0; fn < 2; fn++) {
          accg[fm][fn] = mfma16(af[fm], bg[fn], accg[fm][fn]);
          accu[fm][fn] = mfma16(af[fm], bu[fn], accu[fm][fn]);
        }
    }
    __syncthreads();
  }
#pragma unroll
  for (int fm = 0; fm < 4; fm++)
#pragma unroll
    for (int reg = 0; reg < 4; reg++) {
      int r = tm0 + wm * 64 + fm * 16 + quad * 4 + reg;
#pragma unroll
      for (int fn = 0; fn < 2; fn++) {
        int c = tn0 + wn * 32 + fn * 16 + l16;
        float g = accg[fm][fn][reg];
        float u = accu[fm][fn][reg];
        float h = (g / (1.f + __expf(-g))) * u;
        H[(size_t)r * ISH + c] = f2bf(h);
      }
    }
}

// Fused gate/up + SiLU for routed experts (gathered A rows).
__global__ __launch_bounds__(256, 2) void k_gu_expert(
    const unsigned short* __restrict__ Xb,
    const unsigned short* __restrict__ EgT,  // [E][1024][1024]
    const unsigned short* __restrict__ EuT,
    const int* __restrict__ seg_off,
    const int* __restrict__ ptok,
    unsigned short* __restrict__ Hp)         // [16384][1024] by pair slot
{
  const int e = blockIdx.x >> 6;
  const int mt = blockIdx.x & 63;
  const int s0 = seg_off[e];
  const int cnt = seg_off[e + 1] - s0;
  const int tm0 = mt * 128;
  if (tm0 >= cnt) return;

  __shared__ __align__(16) unsigned short As[128 * BK];
  __shared__ __align__(16) unsigned short Bgs[64 * BK];
  __shared__ __align__(16) unsigned short Bus[64 * BK];

  const int tn0 = blockIdx.y * 64;
  const int tid = threadIdx.x;
  const int wave = tid >> 6, lane = tid & 63;
  const int wm = wave & 1, wn = wave >> 1;
  const int quad = lane >> 4, l16 = lane & 15;
  const int srow = lane >> 3;
  const int scol = (lane & 7) * 8;

  const unsigned short* Bg = EgT + (size_t)e * IMOE * DDIM;
  const unsigned short* Bu = EuT + (size_t)e * IMOE * DDIM;

  int tokr[4];
#pragma unroll
  for (int s = 0; s < 4; s++) {
    int row = tm0 + (wave * 4 + s) * 8 + srow;
    tokr[s] = ptok[s0 + min(row, cnt - 1)];
  }

  floatx4 accg[4][2] = {};
  floatx4 accu[4][2] = {};

  for (int k0 = 0; k0 < DDIM; k0 += BK) {
#pragma unroll
    for (int s = 0; s < 4; s++) {
      int rb = (wave * 4 + s) * 8;
      gload16(Xb + (size_t)tokr[s] * DDIM + k0 + scol, As + rb * BK);
    }
#pragma unroll
    for (int s = 0; s < 2; s++) {
      int rb = (wave * 2 + s) * 8;
      gload16(Bg + (size_t)(tn0 + rb + srow) * DDIM + k0 + scol, Bgs + rb * BK);
      gload16(Bu + (size_t)(tn0 + rb + srow) * DDIM + k0 + scol, Bus + rb * BK);
    }
    __syncthreads();
#pragma unroll
    for (int ks = 0; ks < BK; ks += 32) {
      short8 af[4], bg[2], bu[2];
#pragma unroll
      for (int f = 0; f < 4; f++)
        af[f] = *(const short8*)(As + (wm * 64 + f * 16 + l16) * BK + ks + quad * 8);
#pragma unroll
      for (int f = 0; f < 2; f++) {
        bg[f] = *(const short8*)(Bgs + (wn * 32 + f * 16 + l16) * BK + ks + quad * 8);
        bu[f] = *(const short8*)(Bus + (wn * 32 + f * 16 + l16) * BK + ks + quad * 8);
      }
#pragma unroll
      for (int fm = 0; fm < 4; fm++)
#pragma unroll
        for (int fn = 0; fn < 2; fn++) {
          accg[fm][fn] = mfma16(af[fm], bg[fn], accg[fm][fn]);
          accu[fm][fn] = mfma16(af[fm], bu[fn], accu[fm][fn]);
        }
    }
    __syncthreads();
  }
#pragma unroll
  for (int fm = 0; fm < 4; fm++)
#pragma unroll
    for (int reg = 0; reg < 4; reg++) {
      int rloc = tm0 + wm * 64 + fm * 16 + quad * 4 + reg;
      if (rloc < cnt) {
#pragma unroll
        for (int fn = 0; fn < 2; fn++) {
          int c = tn0 + wn * 32 + fn * 16 + l16;
          float g = accg[fm][fn][reg];
          float u = accu[fm][fn][reg];
          Hp[(size_t)(s0 + rloc) * IMOE + c] = f2bf((g / (1.f + __expf(-g))) * u);
        }
      }
    }
}

// Shared-expert down proj: out = sigmoid_gate[t] * (Hsh @ sd). Writes full out.
__global__ __launch_bounds__(256, 2) void k_down_shared(
    const unsigned short* __restrict__ Hsh,  // [8192][4096]
    const unsigned short* __restrict__ SdT,  // [1024][4096]
    const float* __restrict__ sgate,
    float* __restrict__ out)                 // [8192][1024]
{
  __shared__ __align__(16) unsigned short As[128 * BK];
  __shared__ __align__(16) unsigned short Bs[128 * BK];

  const int tm0 = blockIdx.x * 128;
  const int tn0 = blockIdx.y * 128;
  const int tid = threadIdx.x;
  const int wave = tid >> 6, lane = tid & 63;
  const int wm = wave & 1, wn = wave >> 1;
  const int quad = lane >> 4, l16 = lane & 15;
  const int srow = lane >> 3;
  const int scol = (lane & 7) * 8;

  floatx4 acc[4][4] = {};

  for (int k0 = 0; k0 < ISH; k0 += BK) {
#pragma unroll
    for (int s = 0; s < 4; s++) {
      int rb = (wave * 4 + s) * 8;
      gload16(Hsh + (size_t)(tm0 + rb + srow) * ISH + k0 + scol, As + rb * BK);
      gload16(SdT + (size_t)(tn0 + rb + srow) * ISH + k0 + scol, Bs + rb * BK);
    }
    __syncthreads();
#pragma unroll
    for (int ks = 0; ks < BK; ks += 32) {
      short8 af[4], bfr[4];
#pragma unroll
      for (int f = 0; f < 4; f++) {
        af[f] = *(const short8*)(As + (wm * 64 + f * 16 + l16) * BK + ks + quad * 8);
        bfr[f] = *(const short8*)(Bs + (wn * 64 + f * 16 + l16) * BK + ks + quad * 8);
      }
#pragma unroll
      for (int fm = 0; fm < 4; fm++)
#pragma unroll
        for (int fn = 0; fn < 4; fn++)
          acc[fm][fn] = mfma16(af[fm], bfr[fn], acc[fm][fn]);
    }
    __syncthreads();
  }
#pragma unroll
  for (int fm = 0; fm < 4; fm++)
#pragma unroll
    for (int reg = 0; reg < 4; reg++) {
      int r = tm0 + wm * 64 + fm * 16 + quad * 4 + reg;
      float gt = sgate[r];
#pragma unroll
      for (int fn = 0; fn < 4; fn++) {
        int c = tn0 + wn * 64 + fn * 16 + l16;
        out[(size_t)r * DDIM + c] = gt * acc[fm][fn][reg];
      }
    }
}

// Expert down proj: out[tok] += w_pair * (Hp @ ed[e]) via atomics.
__global__ __launch_bounds__(256, 2) void k_down_expert(
    const unsigned short* __restrict__ Hp,   // [16384][1024]
    const unsigned short* __restrict__ EdT,  // [E][1024][1024]
    const int* __restrict__ seg_off,
    const int* __restrict__ ptok,
    const float* __restrict__ pw,
    float* __restrict__ out)
{
  const int e = blockIdx.x >> 6;
  const int mt = blockIdx.x & 63;
  const int s0 = seg_off[e];
  const int cnt = seg_off[e + 1] - s0;
  const int tm0 = mt * 128;
  if (tm0 >= cnt) return;

  __shared__ __align__(16) unsigned short As[128 * BK];
  __shared__ __align__(16) unsigned short Bs[128 * BK];

  const int tn0 = blockIdx.y * 128;
  const int tid = threadIdx.x;
  const int wave = tid >> 6, lane = tid & 63;
  const int wm = wave & 1, wn = wave >> 1;
  const int quad = lane >> 4, l16 = lane & 15;
  const int srow = lane >> 3;
  const int scol = (lane & 7) * 8;

  const unsigned short* B = EdT + (size_t)e * IMOE * DDIM;

  floatx4 acc[4][4] = {};

  for (int k0 = 0; k0 < IMOE; k0 += BK) {
#pragma unroll
    for (int s = 0; s < 4; s++) {
      int rb = (wave * 4 + s) * 8;
      int rowg = s0 + min(tm0 + rb + srow, cnt - 1);
      gload16(Hp + (size_t)rowg * IMOE + k0 + scol, As + rb * BK);
      gload16(B + (size_t)(tn0 + rb + srow) * IMOE + k0 + scol, Bs + rb * BK);
    }
    __syncthreads();
#pragma unroll
    for (int ks = 0; ks < BK; ks += 32) {
      short8 af[4], bfr[4];
#pragma unroll
      for (int f = 0; f < 4; f++) {
        af[f] = *(const short8*)(As + (wm * 64 + f * 16 + l16) * BK + ks + quad * 8);
        bfr[f] = *(const short8*)(Bs + (wn * 64 + f * 16 + l16) * BK + ks + quad * 8);
      }
#pragma unroll
      for (int fm = 0; fm < 4; fm++)
#pragma unroll
        for (int fn = 0; fn < 4; fn++)
          acc[fm][fn] = mfma16(af[fm], bfr[fn], acc[fm][fn]);
    }
    __syncthreads();
  }
#pragma unroll
  for (int fm = 0; fm < 4; fm++)
#pragma unroll
    for (int reg = 0; reg < 4; reg++) {
      int rloc = tm0 + wm * 64 + fm * 16 + quad * 4 + reg;
      if (rloc < cnt) {
        int p = s0 + rloc;
        int t = ptok[p];
        float w = pw[p];
#pragma unroll
        for (int fn = 0; fn < 4; fn++) {
          int c = tn0 + wn * 64 + fn * 16 + l16;
          atomicAdd(&out[(size_t)t * DDIM + c], w * acc[fm][fn][reg]);
        }
      }
    }
}

// ---------------- launch ----------------

extern "C" void kernel_launch(void* const* d_in, const int* in_sizes, int n_in,
                              void* d_out, int out_size, void* d_ws, size_t ws_size,
                              hipStream_t stream) {
  const float* x   = (const float*)d_in[0];
  const float* gw  = (const float*)d_in[1];
  const float* eg  = (const float*)d_in[2];
  const float* eu  = (const float*)d_in[3];
  const float* ed  = (const float*)d_in[4];
  const float* sg  = (const float*)d_in[5];
  const float* su  = (const float*)d_in[6];
  const float* sd  = (const float*)d_in[7];
  const float* sgw = (const float*)d_in[8];

  float* out    = (float*)d_out;                 // [8192][1024]
  float* logits = out + (size_t)T_TOK * DDIM;    // [8192][8]

  char* ws = (char*)d_ws;
  unsigned short* xb   = (unsigned short*)(ws + 0);            // 16 MB
  unsigned short* egT  = (unsigned short*)(ws + 16777216);     // 16 MB
  unsigned short* euT  = (unsigned short*)(ws + 33554432);     // 16 MB
  unsigned short* edT  = (unsigned short*)(ws + 50331648);     // 16 MB
  unsigned short* sgT  = (unsigned short*)(ws + 67108864);     // 8 MB
  unsigned short* suT  = (unsigned short*)(ws + 75497472);     // 8 MB
  unsigned short* sdT  = (unsigned short*)(ws + 83886080);     // 8 MB
  unsigned short* hsh  = (unsigned short*)(ws + 92274688);     // 64 MB
  unsigned short* hp   = (unsigned short*)(ws + 159383552);    // 32 MB
  int*   topi      = (int*)  (ws + 192937984);   // 16384 ints
  float* topw      = (float*)(ws + 193003520);   // 16384 floats
  float* sgate     = (float*)(ws + 193069056);   // 8192 floats
  int*   ptok      = (int*)  (ws + 193101824);   // 16384 ints
  float* pw        = (float*)(ws + 193167360);   // 16384 floats
  int*   blockhist = (int*)  (ws + 193232896);   // 64*8 ints
  int*   blockbase = (int*)  (ws + 193234944);   // 64*8 ints
  int*   seg_off   = (int*)  (ws + 193236992);   // 9 ints

  k_cast<<<8192, 256, 0, stream>>>(x, xb, T_TOK * DDIM);
  k_transpose_cast<<<dim3(32, 32, 8), dim3(32, 8), 0, stream>>>(eg, egT, DDIM, IMOE);
  k_transpose_cast<<<dim3(32, 32, 8), dim3(32, 8), 0, stream>>>(eu, euT, DDIM, IMOE);
  k_transpose_cast<<<dim3(32, 32, 8), dim3(32, 8), 0, stream>>>(ed, edT, IMOE, DDIM);
  k_transpose_cast<<<dim3(128, 32, 1), dim3(32, 8), 0, stream>>>(sg, sgT, DDIM, ISH);
  k_transpose_cast<<<dim3(128, 32, 1), dim3(32, 8), 0, stream>>>(su, suT, DDIM, ISH);
  k_transpose_cast<<<dim3(32, 128, 1), dim3(32, 8), 0, stream>>>(sd, sdT, ISH, DDIM);

  k_router<<<T_TOK / 4, 256, 0, stream>>>(x, gw, sgw, logits, topi, topw, sgate);
  k_hist<<<64, 256, 0, stream>>>(topi, blockhist);
  k_offsets<<<1, 64, 0, stream>>>(blockhist, seg_off, blockbase);
  k_scatter<<<64, 256, 0, stream>>>(topi, topw, blockbase, ptok, pw);

  k_gu_shared<<<dim3(64, 64), 256, 0, stream>>>(xb, sgT, suT, hsh);
  k_gu_expert<<<dim3(512, 16), 256, 0, stream>>>(xb, egT, euT, seg_off, ptok, hp);
  k_down_shared<<<dim3(64, 8), 256, 0, stream>>>(hsh, sdT, sgate, out);
  k_down_expert<<<dim3(512, 8), 256, 0, stream>>>(hp, edT, seg_off, ptok, pw, out);

  (void)in_sizes; (void)n_in; (void)out_size; (void)ws_size;
}

// Round 3
// 714.511 us; speedup vs baseline: 1.4514x; 1.1691x over previous
//
#include <hip/hip_runtime.h>
#include <hip/hip_bf16.h>
#include <stdint.h>

#define T_TOK 8192
#define DDIM 1024
#define NEXP 8
#define IMOE 1024
#define ISH 4096
#define BK 64

typedef __attribute__((ext_vector_type(8))) short short8;
typedef __attribute__((ext_vector_type(8))) __bf16 bf16x8;
typedef __attribute__((ext_vector_type(4))) float floatx4;

// round-to-nearest-even fp32 -> bf16 bits
__device__ __forceinline__ unsigned short f2bf(float f) {
  union { float f; unsigned u; } v; v.f = f;
  unsigned r = v.u + 0x7fffu + ((v.u >> 16) & 1u);
  return (unsigned short)(r >> 16);
}

__device__ __forceinline__ floatx4 mfma16(short8 a, short8 b, floatx4 c) {
  return __builtin_amdgcn_mfma_f32_16x16x32_bf16(
      __builtin_bit_cast(bf16x8, a), __builtin_bit_cast(bf16x8, b), c, 0, 0, 0);
}

// async global->LDS, 16B per lane; LDS base must be wave-uniform
__device__ __forceinline__ void gload16(const void* g, void* l) {
  __builtin_amdgcn_global_load_lds((const __attribute__((address_space(1))) void*)g,
                                   (__attribute__((address_space(3))) void*)l, 16, 0, 0);
}

// XOR swizzle: LDS 16B-block b of row r holds global block (b ^ (r&7)).
// Staging: lane (srow=lane>>3, sblk=lane&7) fetches global block sblk^srow.
// Read: global block g of row r sits at LDS block g^(r&7).
// Breaks the 16-way same-bank-group conflict of the unswizzled BK=64 layout
// (row stride 128B == 32 banks) down to free 2-way aliasing.

// ---------------- conversion kernels ----------------

__global__ void k_cast(const float* __restrict__ src, unsigned short* __restrict__ dst, int n) {
  int i = (blockIdx.x * blockDim.x + threadIdx.x) * 4;
  if (i < n) {
    float4 v = *(const float4*)(src + i);
    ushort4 o;
    o.x = f2bf(v.x); o.y = f2bf(v.y); o.z = f2bf(v.z); o.w = f2bf(v.w);
    *(ushort4*)(dst + i) = o;
  }
}

// src [batch][R][C] f32 -> dst [batch][C][R] bf16  (B^T layout for GEMM)
__global__ void k_transpose_cast(const float* __restrict__ src, unsigned short* __restrict__ dst,
                                 int R, int C) {
  __shared__ float tile[32][33];
  int b = blockIdx.z;
  int c0 = blockIdx.x * 32, r0 = blockIdx.y * 32;
  const float* s = src + (size_t)b * R * C;
  unsigned short* d = dst + (size_t)b * R * C;
  int tx = threadIdx.x, ty = threadIdx.y;  // 32 x 8
#pragma unroll
  for (int j = 0; j < 32; j += 8)
    tile[ty + j][tx] = s[(size_t)(r0 + ty + j) * C + c0 + tx];
  __syncthreads();
#pragma unroll
  for (int j = 0; j < 32; j += 8)
    d[(size_t)(c0 + ty + j) * R + r0 + tx] = f2bf(tile[tx][ty + j]);
}

// ---------------- router (no global atomics) ----------------

__global__ void k_router(const float* __restrict__ x, const float* __restrict__ gw,
                         const float* __restrict__ sgw, float* __restrict__ logits_out,
                         int* __restrict__ topi, float* __restrict__ topw,
                         float* __restrict__ sgate) {
  int wave = threadIdx.x >> 6;
  int lane = threadIdx.x & 63;
  int t = blockIdx.x * 4 + wave;
  const float* xr = x + (size_t)t * DDIM;
  float acc[9];
#pragma unroll
  for (int j = 0; j < 9; j++) acc[j] = 0.f;
  for (int d = lane; d < DDIM; d += 64) {
    float xv = xr[d];
    const float* g = gw + d * 8;
    float4 g0 = *(const float4*)g;
    float4 g1 = *(const float4*)(g + 4);
    acc[0] += xv * g0.x; acc[1] += xv * g0.y; acc[2] += xv * g0.z; acc[3] += xv * g0.w;
    acc[4] += xv * g1.x; acc[5] += xv * g1.y; acc[6] += xv * g1.z; acc[7] += xv * g1.w;
    acc[8] += xv * sgw[d];
  }
#pragma unroll
  for (int off = 32; off > 0; off >>= 1) {
#pragma unroll
    for (int j = 0; j < 9; j++) acc[j] += __shfl_xor(acc[j], off);
  }
  if (lane == 0) {
#pragma unroll
    for (int j = 0; j < 8; j++) logits_out[t * 8 + j] = acc[j];
    int i0 = 0;
#pragma unroll
    for (int j = 1; j < 8; j++) if (acc[j] > acc[i0]) i0 = j;
    int i1 = -1;
#pragma unroll
    for (int j = 0; j < 8; j++) {
      if (j == i0) continue;
      if (i1 < 0 || acc[j] > acc[i1]) i1 = j;
    }
    float e1 = expf(acc[i1] - acc[i0]);  // e0 = 1
    float inv = 1.f / (1.f + e1);
    topi[t * 2] = i0; topi[t * 2 + 1] = i1;
    topw[t * 2] = inv; topw[t * 2 + 1] = e1 * inv;
    sgate[t] = 1.f / (1.f + expf(-acc[8]));
  }
}

// Counting sort pass 1: per-block expert histogram (LDS atomics only).
__global__ void k_hist(const int* __restrict__ topi, int* __restrict__ blockhist) {
  __shared__ int h[NEXP];
  if (threadIdx.x < NEXP) h[threadIdx.x] = 0;
  __syncthreads();
  int i = blockIdx.x * 256 + threadIdx.x;  // pair index
  atomicAdd(&h[topi[i]], 1);
  __syncthreads();
  if (threadIdx.x < NEXP) blockhist[blockIdx.x * NEXP + threadIdx.x] = h[threadIdx.x];
}

// Pass 2: per-(block,expert) base offsets + expert segment offsets. Tiny.
__global__ void k_offsets(const int* __restrict__ blockhist, int* __restrict__ seg_off,
                          int* __restrict__ blockbase) {
  if (threadIdx.x == 0) {
    int tot[NEXP];
#pragma unroll
    for (int e = 0; e < NEXP; e++) tot[e] = 0;
    for (int b = 0; b < 64; b++)
      for (int e = 0; e < NEXP; e++) {
        blockbase[b * NEXP + e] = tot[e];
        tot[e] += blockhist[b * NEXP + e];
      }
    int s = 0;
    for (int e = 0; e < NEXP; e++) { seg_off[e] = s; s += tot[e]; }
    seg_off[NEXP] = s;
    for (int b = 0; b < 64; b++)
      for (int e = 0; e < NEXP; e++) blockbase[b * NEXP + e] += seg_off[e];
  }
}

// Pass 3: scatter with per-block LDS cursors (no global atomics).
__global__ void k_scatter(const int* __restrict__ topi, const float* __restrict__ topw,
                          const int* __restrict__ blockbase,
                          int* __restrict__ ptok, float* __restrict__ pw) {
  __shared__ int cur[NEXP];
  if (threadIdx.x < NEXP) cur[threadIdx.x] = blockbase[blockIdx.x * NEXP + threadIdx.x];
  __syncthreads();
  int i = blockIdx.x * 256 + threadIdx.x;  // pair index
  int e = topi[i];
  int pos = atomicAdd(&cur[e], 1);
  ptok[pos] = i >> 1;
  pw[pos] = topw[i];
}

// ---------------- GEMM kernels (MFMA bf16 16x16x32, XOR-swizzled LDS) ----------------
// Fused gate/up + SiLU, shared expert: C tile 128(M) x 64(N), dual-B accs.
__global__ __launch_bounds__(256, 2) void k_gu_shared(
    const unsigned short* __restrict__ Xb,   // [8192][1024]
    const unsigned short* __restrict__ BgT,  // [4096][1024]
    const unsigned short* __restrict__ BuT,  // [4096][1024]
    unsigned short* __restrict__ H)          // [8192][4096]
{
  __shared__ __align__(16) unsigned short As[128 * BK];
  __shared__ __align__(16) unsigned short Bgs[64 * BK];
  __shared__ __align__(16) unsigned short Bus[64 * BK];

  const int tm0 = blockIdx.x * 128;
  const int tn0 = blockIdx.y * 64;
  const int tid = threadIdx.x;
  const int wave = tid >> 6, lane = tid & 63;
  const int wm = wave & 1, wn = wave >> 1;
  const int quad = lane >> 4, l16 = lane & 15;
  const int srow = lane >> 3;                        // 8 lanes per 64-elem row
  const int scol = ((lane & 7) ^ srow) * 8;          // swizzled global col block

  floatx4 accg[4][2] = {};
  floatx4 accu[4][2] = {};

  for (int k0 = 0; k0 < DDIM; k0 += BK) {
#pragma unroll
    for (int s = 0; s < 4; s++) {
      int rb = (wave * 4 + s) * 8;
      gload16(Xb + (size_t)(tm0 + rb + srow) * DDIM + k0 + scol, As + rb * BK);
    }
#pragma unroll
    for (int s = 0; s < 2; s++) {
      int rb = (wave * 2 + s) * 8;
      gload16(BgT + (size_t)(tn0 + rb + srow) * DDIM + k0 + scol, Bgs + rb * BK);
      gload16(BuT + (size_t)(tn0 + rb + srow) * DDIM + k0 + scol, Bus + rb * BK);
    }
    __syncthreads();
#pragma unroll
    for (int ks = 0; ks < BK; ks += 32) {
      short8 af[4], bg[2], bu[2];
#pragma unroll
      for (int f = 0; f < 4; f++) {
        int r = wm * 64 + f * 16 + l16;
        af[f] = *(const short8*)(As + r * BK + ((((ks >> 3) + quad) ^ (r & 7)) << 3));
      }
#pragma unroll
      for (int f = 0; f < 2; f++) {
        int r = wn * 32 + f * 16 + l16;
        int off = r * BK + ((((ks >> 3) + quad) ^ (r & 7)) << 3);
        bg[f] = *(const short8*)(Bgs + off);
        bu[f] = *(const short8*)(Bus + off);
      }
#pragma unroll
      for (int fm = 0; fm < 4; fm++)
#pragma unroll
        for (int fn = 0; fn < 2; fn++) {
          accg[fm][fn] = mfma16(af[fm], bg[fn], accg[fm][fn]);
          accu[fm][fn] = mfma16(af[fm], bu[fn], accu[fm][fn]);
        }
    }
    __syncthreads();
  }
#pragma unroll
  for (int fm = 0; fm < 4; fm++)
#pragma unroll
    for (int reg = 0; reg < 4; reg++) {
      int r = tm0 + wm * 64 + fm * 16 + quad * 4 + reg;
#pragma unroll
      for (int fn = 0; fn < 2; fn++) {
        int c = tn0 + wn * 32 + fn * 16 + l16;
        float g = accg[fm][fn][reg];
        float u = accu[fm][fn][reg];
        float h = (g / (1.f + __expf(-g))) * u;
        H[(size_t)r * ISH + c] = f2bf(h);
      }
    }
}

// Fused gate/up + SiLU for routed experts (gathered A rows).
__global__ __launch_bounds__(256, 2) void k_gu_expert(
    const unsigned short* __restrict__ Xb,
    const unsigned short* __restrict__ EgT,  // [E][1024][1024]
    const unsigned short* __restrict__ EuT,
    const int* __restrict__ seg_off,
    const int* __restrict__ ptok,
    unsigned short* __restrict__ Hp)         // [16384][1024] by pair slot
{
  const int e = blockIdx.x >> 6;
  const int mt = blockIdx.x & 63;
  const int s0 = seg_off[e];
  const int cnt = seg_off[e + 1] - s0;
  const int tm0 = mt * 128;
  if (tm0 >= cnt) return;

  __shared__ __align__(16) unsigned short As[128 * BK];
  __shared__ __align__(16) unsigned short Bgs[64 * BK];
  __shared__ __align__(16) unsigned short Bus[64 * BK];

  const int tn0 = blockIdx.y * 64;
  const int tid = threadIdx.x;
  const int wave = tid >> 6, lane = tid & 63;
  const int wm = wave & 1, wn = wave >> 1;
  const int quad = lane >> 4, l16 = lane & 15;
  const int srow = lane >> 3;
  const int scol = ((lane & 7) ^ srow) * 8;

  const unsigned short* Bg = EgT + (size_t)e * IMOE * DDIM;
  const unsigned short* Bu = EuT + (size_t)e * IMOE * DDIM;

  int tokr[4];
#pragma unroll
  for (int s = 0; s < 4; s++) {
    int row = tm0 + (wave * 4 + s) * 8 + srow;
    tokr[s] = ptok[s0 + min(row, cnt - 1)];
  }

  floatx4 accg[4][2] = {};
  floatx4 accu[4][2] = {};

  for (int k0 = 0; k0 < DDIM; k0 += BK) {
#pragma unroll
    for (int s = 0; s < 4; s++) {
      int rb = (wave * 4 + s) * 8;
      gload16(Xb + (size_t)tokr[s] * DDIM + k0 + scol, As + rb * BK);
    }
#pragma unroll
    for (int s = 0; s < 2; s++) {
      int rb = (wave * 2 + s) * 8;
      gload16(Bg + (size_t)(tn0 + rb + srow) * DDIM + k0 + scol, Bgs + rb * BK);
      gload16(Bu + (size_t)(tn0 + rb + srow) * DDIM + k0 + scol, Bus + rb * BK);
    }
    __syncthreads();
#pragma unroll
    for (int ks = 0; ks < BK; ks += 32) {
      short8 af[4], bg[2], bu[2];
#pragma unroll
      for (int f = 0; f < 4; f++) {
        int r = wm * 64 + f * 16 + l16;
        af[f] = *(const short8*)(As + r * BK + ((((ks >> 3) + quad) ^ (r & 7)) << 3));
      }
#pragma unroll
      for (int f = 0; f < 2; f++) {
        int r = wn * 32 + f * 16 + l16;
        int off = r * BK + ((((ks >> 3) + quad) ^ (r & 7)) << 3);
        bg[f] = *(const short8*)(Bgs + off);
        bu[f] = *(const short8*)(Bus + off);
      }
#pragma unroll
      for (int fm = 0; fm < 4; fm++)
#pragma unroll
        for (int fn = 0; fn < 2; fn++) {
          accg[fm][fn] = mfma16(af[fm], bg[fn], accg[fm][fn]);
          accu[fm][fn] = mfma16(af[fm], bu[fn], accu[fm][fn]);
        }
    }
    __syncthreads();
  }
#pragma unroll
  for (int fm = 0; fm < 4; fm++)
#pragma unroll
    for (int reg = 0; reg < 4; reg++) {
      int rloc = tm0 + wm * 64 + fm * 16 + quad * 4 + reg;
      if (rloc < cnt) {
#pragma unroll
        for (int fn = 0; fn < 2; fn++) {
          int c = tn0 + wn * 32 + fn * 16 + l16;
          float g = accg[fm][fn][reg];
          float u = accu[fm][fn][reg];
          Hp[(size_t)(s0 + rloc) * IMOE + c] = f2bf((g / (1.f + __expf(-g))) * u);
        }
      }
    }
}

// Shared-expert down proj: out = sigmoid_gate[t] * (Hsh @ sd). Writes full out.
__global__ __launch_bounds__(256, 2) void k_down_shared(
    const unsigned short* __restrict__ Hsh,  // [8192][4096]
    const unsigned short* __restrict__ SdT,  // [1024][4096]
    const float* __restrict__ sgate,
    float* __restrict__ out)                 // [8192][1024]
{
  __shared__ __align__(16) unsigned short As[128 * BK];
  __shared__ __align__(16) unsigned short Bs[128 * BK];

  const int tm0 = blockIdx.x * 128;
  const int tn0 = blockIdx.y * 128;
  const int tid = threadIdx.x;
  const int wave = tid >> 6, lane = tid & 63;
  const int wm = wave & 1, wn = wave >> 1;
  const int quad = lane >> 4, l16 = lane & 15;
  const int srow = lane >> 3;
  const int scol = ((lane & 7) ^ srow) * 8;

  floatx4 acc[4][4] = {};

  for (int k0 = 0; k0 < ISH; k0 += BK) {
#pragma unroll
    for (int s = 0; s < 4; s++) {
      int rb = (wave * 4 + s) * 8;
      gload16(Hsh + (size_t)(tm0 + rb + srow) * ISH + k0 + scol, As + rb * BK);
      gload16(SdT + (size_t)(tn0 + rb + srow) * ISH + k0 + scol, Bs + rb * BK);
    }
    __syncthreads();
#pragma unroll
    for (int ks = 0; ks < BK; ks += 32) {
      short8 af[4], bfr[4];
#pragma unroll
      for (int f = 0; f < 4; f++) {
        int ra = wm * 64 + f * 16 + l16;
        int rb2 = wn * 64 + f * 16 + l16;
        af[f] = *(const short8*)(As + ra * BK + ((((ks >> 3) + quad) ^ (ra & 7)) << 3));
        bfr[f] = *(const short8*)(Bs + rb2 * BK + ((((ks >> 3) + quad) ^ (rb2 & 7)) << 3));
      }
#pragma unroll
      for (int fm = 0; fm < 4; fm++)
#pragma unroll
        for (int fn = 0; fn < 4; fn++)
          acc[fm][fn] = mfma16(af[fm], bfr[fn], acc[fm][fn]);
    }
    __syncthreads();
  }
#pragma unroll
  for (int fm = 0; fm < 4; fm++)
#pragma unroll
    for (int reg = 0; reg < 4; reg++) {
      int r = tm0 + wm * 64 + fm * 16 + quad * 4 + reg;
      float gt = sgate[r];
#pragma unroll
      for (int fn = 0; fn < 4; fn++) {
        int c = tn0 + wn * 64 + fn * 16 + l16;
        out[(size_t)r * DDIM + c] = gt * acc[fm][fn][reg];
      }
    }
}

// Expert down proj: out[tok] += w_pair * (Hp @ ed[e]) via atomics.
__global__ __launch_bounds__(256, 2) void k_down_expert(
    const unsigned short* __restrict__ Hp,   // [16384][1024]
    const unsigned short* __restrict__ EdT,  // [E][1024][1024]
    const int* __restrict__ seg_off,
    const int* __restrict__ ptok,
    const float* __restrict__ pw,
    float* __restrict__ out)
{
  const int e = blockIdx.x >> 6;
  const int mt = blockIdx.x & 63;
  const int s0 = seg_off[e];
  const int cnt = seg_off[e + 1] - s0;
  const int tm0 = mt * 128;
  if (tm0 >= cnt) return;

  __shared__ __align__(16) unsigned short As[128 * BK];
  __shared__ __align__(16) unsigned short Bs[128 * BK];

  const int tn0 = blockIdx.y * 128;
  const int tid = threadIdx.x;
  const int wave = tid >> 6, lane = tid & 63;
  const int wm = wave & 1, wn = wave >> 1;
  const int quad = lane >> 4, l16 = lane & 15;
  const int srow = lane >> 3;
  const int scol = ((lane & 7) ^ srow) * 8;

  const unsigned short* B = EdT + (size_t)e * IMOE * DDIM;

  floatx4 acc[4][4] = {};

  for (int k0 = 0; k0 < IMOE; k0 += BK) {
#pragma unroll
    for (int s = 0; s < 4; s++) {
      int rb = (wave * 4 + s) * 8;
      int rowg = s0 + min(tm0 + rb + srow, cnt - 1);
      gload16(Hp + (size_t)rowg * IMOE + k0 + scol, As + rb * BK);
      gload16(B + (size_t)(tn0 + rb + srow) * IMOE + k0 + scol, Bs + rb * BK);
    }
    __syncthreads();
#pragma unroll
    for (int ks = 0; ks < BK; ks += 32) {
      short8 af[4], bfr[4];
#pragma unroll
      for (int f = 0; f < 4; f++) {
        int ra = wm * 64 + f * 16 + l16;
        int rb2 = wn * 64 + f * 16 + l16;
        af[f] = *(const short8*)(As + ra * BK + ((((ks >> 3) + quad) ^ (ra & 7)) << 3));
        bfr[f] = *(const short8*)(Bs + rb2 * BK + ((((ks >> 3) + quad) ^ (rb2 & 7)) << 3));
      }
#pragma unroll
      for (int fm = 0; fm < 4; fm++)
#pragma unroll
        for (int fn = 0; fn < 4; fn++)
          acc[fm][fn] = mfma16(af[fm], bfr[fn], acc[fm][fn]);
    }
    __syncthreads();
  }
#pragma unroll
  for (int fm = 0; fm < 4; fm++)
#pragma unroll
    for (int reg = 0; reg < 4; reg++) {
      int rloc = tm0 + wm * 64 + fm * 16 + quad * 4 + reg;
      if (rloc < cnt) {
        int p = s0 + rloc;
        int t = ptok[p];
        float w = pw[p];
#pragma unroll
        for (int fn = 0; fn < 4; fn++) {
          int c = tn0 + wn * 64 + fn * 16 + l16;
          atomicAdd(&out[(size_t)t * DDIM + c], w * acc[fm][fn][reg]);
        }
      }
    }
}

// ---------------- launch ----------------

extern "C" void kernel_launch(void* const* d_in, const int* in_sizes, int n_in,
                              void* d_out, int out_size, void* d_ws, size_t ws_size,
                              hipStream_t stream) {
  const float* x   = (const float*)d_in[0];
  const float* gw  = (const float*)d_in[1];
  const float* eg  = (const float*)d_in[2];
  const float* eu  = (const float*)d_in[3];
  const float* ed  = (const float*)d_in[4];
  const float* sg  = (const float*)d_in[5];
  const float* su  = (const float*)d_in[6];
  const float* sd  = (const float*)d_in[7];
  const float* sgw = (const float*)d_in[8];

  float* out    = (float*)d_out;                 // [8192][1024]
  float* logits = out + (size_t)T_TOK * DDIM;    // [8192][8]

  char* ws = (char*)d_ws;
  unsigned short* xb   = (unsigned short*)(ws + 0);            // 16 MB
  unsigned short* egT  = (unsigned short*)(ws + 16777216);     // 16 MB
  unsigned short* euT  = (unsigned short*)(ws + 33554432);     // 16 MB
  unsigned short* edT  = (unsigned short*)(ws + 50331648);     // 16 MB
  unsigned short* sgT  = (unsigned short*)(ws + 67108864);     // 8 MB
  unsigned short* suT  = (unsigned short*)(ws + 75497472);     // 8 MB
  unsigned short* sdT  = (unsigned short*)(ws + 83886080);     // 8 MB
  unsigned short* hsh  = (unsigned short*)(ws + 92274688);     // 64 MB
  unsigned short* hp   = (unsigned short*)(ws + 159383552);    // 32 MB
  int*   topi      = (int*)  (ws + 192937984);   // 16384 ints
  float* topw      = (float*)(ws + 193003520);   // 16384 floats
  float* sgate     = (float*)(ws + 193069056);   // 8192 floats
  int*   ptok      = (int*)  (ws + 193101824);   // 16384 ints
  float* pw        = (float*)(ws + 193167360);   // 16384 floats
  int*   blockhist = (int*)  (ws + 193232896);   // 64*8 ints
  int*   blockbase = (int*)  (ws + 193234944);   // 64*8 ints
  int*   seg_off   = (int*)  (ws + 193236992);   // 9 ints

  k_cast<<<8192, 256, 0, stream>>>(x, xb, T_TOK * DDIM);
  k_transpose_cast<<<dim3(32, 32, 8), dim3(32, 8), 0, stream>>>(eg, egT, DDIM, IMOE);
  k_transpose_cast<<<dim3(32, 32, 8), dim3(32, 8), 0, stream>>>(eu, euT, DDIM, IMOE);
  k_transpose_cast<<<dim3(32, 32, 8), dim3(32, 8), 0, stream>>>(ed, edT, IMOE, DDIM);
  k_transpose_cast<<<dim3(128, 32, 1), dim3(32, 8), 0, stream>>>(sg, sgT, DDIM, ISH);
  k_transpose_cast<<<dim3(128, 32, 1), dim3(32, 8), 0, stream>>>(su, suT, DDIM, ISH);
  k_transpose_cast<<<dim3(32, 128, 1), dim3(32, 8), 0, stream>>>(sd, sdT, ISH, DDIM);

  k_router<<<T_TOK / 4, 256, 0, stream>>>(x, gw, sgw, logits, topi, topw, sgate);
  k_hist<<<64, 256, 0, stream>>>(topi, blockhist);
  k_offsets<<<1, 64, 0, stream>>>(blockhist, seg_off, blockbase);
  k_scatter<<<64, 256, 0, stream>>>(topi, topw, blockbase, ptok, pw);

  k_gu_shared<<<dim3(64, 64), 256, 0, stream>>>(xb, sgT, suT, hsh);
  k_gu_expert<<<dim3(512, 16), 256, 0, stream>>>(xb, egT, euT, seg_off, ptok, hp);
  k_down_shared<<<dim3(64, 8), 256, 0, stream>>>(hsh, sdT, sgate, out);
  k_down_expert<<<dim3(512, 8), 256, 0, stream>>>(hp, edT, seg_off, ptok, pw, out);

  (void)in_sizes; (void)n_in; (void)out_size; (void)ws_size;
}

// Round 4
// 691.459 us; speedup vs baseline: 1.4997x; 1.0333x over previous
//
#include <hip/hip_runtime.h>
#include <hip/hip_bf16.h>
#include <stdint.h>

#define T_TOK 8192
#define DDIM 1024
#define NEXP 8
#define IMOE 1024
#define ISH 4096
#define BK 64
#define PADTOT 17408  // 16384 pairs + 8*128 max padding

typedef __attribute__((ext_vector_type(8))) short short8;
typedef __attribute__((ext_vector_type(8))) __bf16 bf16x8;
typedef __attribute__((ext_vector_type(4))) float floatx4;

// round-to-nearest-even fp32 -> bf16 bits
__device__ __forceinline__ unsigned short f2bf(float f) {
  union { float f; unsigned u; } v; v.f = f;
  unsigned r = v.u + 0x7fffu + ((v.u >> 16) & 1u);
  return (unsigned short)(r >> 16);
}

__device__ __forceinline__ floatx4 mfma16(short8 a, short8 b, floatx4 c) {
  return __builtin_amdgcn_mfma_f32_16x16x32_bf16(
      __builtin_bit_cast(bf16x8, a), __builtin_bit_cast(bf16x8, b), c, 0, 0, 0);
}

// async global->LDS, 16B per lane; LDS base must be wave-uniform
__device__ __forceinline__ void gload16(const void* g, void* l) {
  __builtin_amdgcn_global_load_lds((const __attribute__((address_space(1))) void*)g,
                                   (__attribute__((address_space(3))) void*)l, 16, 0, 0);
}

// XOR swizzle: LDS 16B-block b of row r holds global block (b ^ (r&7)).
// Breaks the 16-way bank-group conflict of the BK=64 row stride (128B == 32 banks).

// ---------------- conversion kernels ----------------

__global__ void k_cast(const float* __restrict__ src, unsigned short* __restrict__ dst, int n) {
  int i = (blockIdx.x * blockDim.x + threadIdx.x) * 4;
  if (i < n) {
    float4 v = *(const float4*)(src + i);
    ushort4 o;
    o.x = f2bf(v.x); o.y = f2bf(v.y); o.z = f2bf(v.z); o.w = f2bf(v.w);
    *(ushort4*)(dst + i) = o;
  }
}

// src [batch][R][C] f32 -> dst [batch][C][R] bf16  (B^T layout for GEMM)
__global__ void k_transpose_cast(const float* __restrict__ src, unsigned short* __restrict__ dst,
                                 int R, int C) {
  __shared__ float tile[32][33];
  int b = blockIdx.z;
  int c0 = blockIdx.x * 32, r0 = blockIdx.y * 32;
  const float* s = src + (size_t)b * R * C;
  unsigned short* d = dst + (size_t)b * R * C;
  int tx = threadIdx.x, ty = threadIdx.y;  // 32 x 8
#pragma unroll
  for (int j = 0; j < 32; j += 8)
    tile[ty + j][tx] = s[(size_t)(r0 + ty + j) * C + c0 + tx];
  __syncthreads();
#pragma unroll
  for (int j = 0; j < 32; j += 8)
    d[(size_t)(c0 + ty + j) * R + r0 + tx] = f2bf(tile[tx][ty + j]);
}

// ---------------- router (no global atomics) ----------------

__global__ void k_router(const float* __restrict__ x, const float* __restrict__ gw,
                         const float* __restrict__ sgw, float* __restrict__ logits_out,
                         int* __restrict__ topi, float* __restrict__ topw,
                         float* __restrict__ sgate) {
  int wave = threadIdx.x >> 6;
  int lane = threadIdx.x & 63;
  int t = blockIdx.x * 4 + wave;
  const float* xr = x + (size_t)t * DDIM;
  float acc[9];
#pragma unroll
  for (int j = 0; j < 9; j++) acc[j] = 0.f;
  for (int d = lane; d < DDIM; d += 64) {
    float xv = xr[d];
    const float* g = gw + d * 8;
    float4 g0 = *(const float4*)g;
    float4 g1 = *(const float4*)(g + 4);
    acc[0] += xv * g0.x; acc[1] += xv * g0.y; acc[2] += xv * g0.z; acc[3] += xv * g0.w;
    acc[4] += xv * g1.x; acc[5] += xv * g1.y; acc[6] += xv * g1.z; acc[7] += xv * g1.w;
    acc[8] += xv * sgw[d];
  }
#pragma unroll
  for (int off = 32; off > 0; off >>= 1) {
#pragma unroll
    for (int j = 0; j < 9; j++) acc[j] += __shfl_xor(acc[j], off);
  }
  if (lane == 0) {
#pragma unroll
    for (int j = 0; j < 8; j++) logits_out[t * 8 + j] = acc[j];
    int i0 = 0;
#pragma unroll
    for (int j = 1; j < 8; j++) if (acc[j] > acc[i0]) i0 = j;
    int i1 = -1;
#pragma unroll
    for (int j = 0; j < 8; j++) {
      if (j == i0) continue;
      if (i1 < 0 || acc[j] > acc[i1]) i1 = j;
    }
    float e1 = expf(acc[i1] - acc[i0]);  // e0 = 1
    float inv = 1.f / (1.f + e1);
    topi[t * 2] = i0; topi[t * 2 + 1] = i1;
    topw[t * 2] = inv; topw[t * 2 + 1] = e1 * inv;
    sgate[t] = 1.f / (1.f + expf(-acc[8]));
  }
}

// Counting sort pass 1: per-block expert histogram (LDS atomics only).
__global__ void k_hist(const int* __restrict__ topi, int* __restrict__ blockhist) {
  __shared__ int h[NEXP];
  if (threadIdx.x < NEXP) h[threadIdx.x] = 0;
  __syncthreads();
  int i = blockIdx.x * 256 + threadIdx.x;  // pair index
  atomicAdd(&h[topi[i]], 1);
  __syncthreads();
  if (threadIdx.x < NEXP) blockhist[blockIdx.x * NEXP + threadIdx.x] = h[threadIdx.x];
}

// Pass 2: padded segment offsets (multiples of 128) + per-block bases + real counts.
__global__ void k_offsets(const int* __restrict__ blockhist, int* __restrict__ pseg,
                          int* __restrict__ rcnt, int* __restrict__ blockbase) {
  if (threadIdx.x == 0) {
    int tot[NEXP];
#pragma unroll
    for (int e = 0; e < NEXP; e++) tot[e] = 0;
    for (int b = 0; b < 64; b++)
      for (int e = 0; e < NEXP; e++) {
        blockbase[b * NEXP + e] = tot[e];
        tot[e] += blockhist[b * NEXP + e];
      }
    int s = 0;
    for (int e = 0; e < NEXP; e++) {
      rcnt[e] = tot[e];
      pseg[e] = s;
      s += (tot[e] + 127) & ~127;  // pad each segment to 128
    }
    pseg[NEXP] = s;
    for (int b = 0; b < 64; b++)
      for (int e = 0; e < NEXP; e++) blockbase[b * NEXP + e] += pseg[e];
  }
}

// Pass 3: scatter with per-block LDS cursors (no global atomics).
__global__ void k_scatter(const int* __restrict__ topi, const float* __restrict__ topw,
                          const int* __restrict__ blockbase,
                          int* __restrict__ ptok, float* __restrict__ pw) {
  __shared__ int cur[NEXP];
  if (threadIdx.x < NEXP) cur[threadIdx.x] = blockbase[blockIdx.x * NEXP + threadIdx.x];
  __syncthreads();
  int i = blockIdx.x * 256 + threadIdx.x;  // pair index
  int e = topi[i];
  int pos = atomicAdd(&cur[e], 1);
  ptok[pos] = i >> 1;
  pw[pos] = topw[i];
}

// Pass 4: physically gather X rows into contiguous pair-slot order (bf16 copy).
// Pad / unwritten slots (ptok poisoned) -> zero rows.
__global__ void k_gather(const unsigned short* __restrict__ xb, const int* __restrict__ ptok,
                         unsigned short* __restrict__ xg) {
  int row = blockIdx.x * 2 + (threadIdx.x >> 7);
  int col = (threadIdx.x & 127) * 8;
  int tok = ptok[row];
  uint4 v = make_uint4(0, 0, 0, 0);
  if (tok >= 0 && tok < T_TOK) v = *(const uint4*)(xb + (size_t)tok * DDIM + col);
  *(uint4*)(xg + (size_t)row * DDIM + col) = v;
}

// ---------------- GEMM kernels (MFMA bf16 16x16x32, XOR-swizzled LDS) ----------------
// Fused gate/up + SiLU, shared expert: C tile 128(M) x 64(N), dual-B accs.
__global__ __launch_bounds__(256, 2) void k_gu_shared(
    const unsigned short* __restrict__ Xb,   // [8192][1024]
    const unsigned short* __restrict__ BgT,  // [4096][1024]
    const unsigned short* __restrict__ BuT,  // [4096][1024]
    unsigned short* __restrict__ H)          // [8192][4096]
{
  __shared__ __align__(16) unsigned short As[128 * BK];
  __shared__ __align__(16) unsigned short Bgs[64 * BK];
  __shared__ __align__(16) unsigned short Bus[64 * BK];

  const int tm0 = blockIdx.x * 128;
  const int tn0 = blockIdx.y * 64;
  const int tid = threadIdx.x;
  const int wave = tid >> 6, lane = tid & 63;
  const int wm = wave & 1, wn = wave >> 1;
  const int quad = lane >> 4, l16 = lane & 15;
  const int srow = lane >> 3;                        // 8 lanes per 64-elem row
  const int scol = ((lane & 7) ^ srow) * 8;          // swizzled global col block

  floatx4 accg[4][2] = {};
  floatx4 accu[4][2] = {};

  for (int k0 = 0; k0 < DDIM; k0 += BK) {
#pragma unroll
    for (int s = 0; s < 4; s++) {
      int rb = (wave * 4 + s) * 8;
      gload16(Xb + (size_t)(tm0 + rb + srow) * DDIM + k0 + scol, As + rb * BK);
    }
#pragma unroll
    for (int s = 0; s < 2; s++) {
      int rb = (wave * 2 + s) * 8;
      gload16(BgT + (size_t)(tn0 + rb + srow) * DDIM + k0 + scol, Bgs + rb * BK);
      gload16(BuT + (size_t)(tn0 + rb + srow) * DDIM + k0 + scol, Bus + rb * BK);
    }
    __syncthreads();
#pragma unroll
    for (int ks = 0; ks < BK; ks += 32) {
      short8 af[4], bg[2], bu[2];
#pragma unroll
      for (int f = 0; f < 4; f++) {
        int r = wm * 64 + f * 16 + l16;
        af[f] = *(const short8*)(As + r * BK + ((((ks >> 3) + quad) ^ (r & 7)) << 3));
      }
#pragma unroll
      for (int f = 0; f < 2; f++) {
        int r = wn * 32 + f * 16 + l16;
        int off = r * BK + ((((ks >> 3) + quad) ^ (r & 7)) << 3);
        bg[f] = *(const short8*)(Bgs + off);
        bu[f] = *(const short8*)(Bus + off);
      }
#pragma unroll
      for (int fm = 0; fm < 4; fm++)
#pragma unroll
        for (int fn = 0; fn < 2; fn++) {
          accg[fm][fn] = mfma16(af[fm], bg[fn], accg[fm][fn]);
          accu[fm][fn] = mfma16(af[fm], bu[fn], accu[fm][fn]);
        }
    }
    __syncthreads();
  }
#pragma unroll
  for (int fm = 0; fm < 4; fm++)
#pragma unroll
    for (int reg = 0; reg < 4; reg++) {
      int r = tm0 + wm * 64 + fm * 16 + quad * 4 + reg;
#pragma unroll
      for (int fn = 0; fn < 2; fn++) {
        int c = tn0 + wn * 32 + fn * 16 + l16;
        float g = accg[fm][fn][reg];
        float u = accu[fm][fn][reg];
        float h = (g / (1.f + __expf(-g))) * u;
        H[(size_t)r * ISH + c] = f2bf(h);
      }
    }
}

// Fused gate/up + SiLU for routed experts — sequential A from gathered Xg.
__global__ __launch_bounds__(256, 2) void k_gu_expert(
    const unsigned short* __restrict__ Xg,   // [PADTOT][1024] gathered
    const unsigned short* __restrict__ EgT,  // [E][1024][1024]
    const unsigned short* __restrict__ EuT,
    const int* __restrict__ pseg,
    unsigned short* __restrict__ Hp)         // [PADTOT][1024] by pair slot
{
  const int m0 = blockIdx.x * 128;
  if (m0 >= pseg[NEXP]) return;
  int e = 0;
#pragma unroll
  for (int j = 1; j < NEXP; j++) if (m0 >= pseg[j]) e = j;

  __shared__ __align__(16) unsigned short As[128 * BK];
  __shared__ __align__(16) unsigned short Bgs[64 * BK];
  __shared__ __align__(16) unsigned short Bus[64 * BK];

  const int tn0 = blockIdx.y * 64;
  const int tid = threadIdx.x;
  const int wave = tid >> 6, lane = tid & 63;
  const int wm = wave & 1, wn = wave >> 1;
  const int quad = lane >> 4, l16 = lane & 15;
  const int srow = lane >> 3;
  const int scol = ((lane & 7) ^ srow) * 8;

  const unsigned short* Bg = EgT + (size_t)e * IMOE * DDIM;
  const unsigned short* Bu = EuT + (size_t)e * IMOE * DDIM;

  floatx4 accg[4][2] = {};
  floatx4 accu[4][2] = {};

  for (int k0 = 0; k0 < DDIM; k0 += BK) {
#pragma unroll
    for (int s = 0; s < 4; s++) {
      int rb = (wave * 4 + s) * 8;
      gload16(Xg + (size_t)(m0 + rb + srow) * DDIM + k0 + scol, As + rb * BK);
    }
#pragma unroll
    for (int s = 0; s < 2; s++) {
      int rb = (wave * 2 + s) * 8;
      gload16(Bg + (size_t)(tn0 + rb + srow) * DDIM + k0 + scol, Bgs + rb * BK);
      gload16(Bu + (size_t)(tn0 + rb + srow) * DDIM + k0 + scol, Bus + rb * BK);
    }
    __syncthreads();
#pragma unroll
    for (int ks = 0; ks < BK; ks += 32) {
      short8 af[4], bg[2], bu[2];
#pragma unroll
      for (int f = 0; f < 4; f++) {
        int r = wm * 64 + f * 16 + l16;
        af[f] = *(const short8*)(As + r * BK + ((((ks >> 3) + quad) ^ (r & 7)) << 3));
      }
#pragma unroll
      for (int f = 0; f < 2; f++) {
        int r = wn * 32 + f * 16 + l16;
        int off = r * BK + ((((ks >> 3) + quad) ^ (r & 7)) << 3);
        bg[f] = *(const short8*)(Bgs + off);
        bu[f] = *(const short8*)(Bus + off);
      }
#pragma unroll
      for (int fm = 0; fm < 4; fm++)
#pragma unroll
        for (int fn = 0; fn < 2; fn++) {
          accg[fm][fn] = mfma16(af[fm], bg[fn], accg[fm][fn]);
          accu[fm][fn] = mfma16(af[fm], bu[fn], accu[fm][fn]);
        }
    }
    __syncthreads();
  }
#pragma unroll
  for (int fm = 0; fm < 4; fm++)
#pragma unroll
    for (int reg = 0; reg < 4; reg++) {
      int r = m0 + wm * 64 + fm * 16 + quad * 4 + reg;
#pragma unroll
      for (int fn = 0; fn < 2; fn++) {
        int c = tn0 + wn * 32 + fn * 16 + l16;
        float g = accg[fm][fn][reg];
        float u = accu[fm][fn][reg];
        Hp[(size_t)r * IMOE + c] = f2bf((g / (1.f + __expf(-g))) * u);
      }
    }
}

// Shared-expert down proj: out = sigmoid_gate[t] * (Hsh @ sd). Writes full out.
__global__ __launch_bounds__(256, 2) void k_down_shared(
    const unsigned short* __restrict__ Hsh,  // [8192][4096]
    const unsigned short* __restrict__ SdT,  // [1024][4096]
    const float* __restrict__ sgate,
    float* __restrict__ out)                 // [8192][1024]
{
  __shared__ __align__(16) unsigned short As[128 * BK];
  __shared__ __align__(16) unsigned short Bs[128 * BK];

  const int tm0 = blockIdx.x * 128;
  const int tn0 = blockIdx.y * 128;
  const int tid = threadIdx.x;
  const int wave = tid >> 6, lane = tid & 63;
  const int wm = wave & 1, wn = wave >> 1;
  const int quad = lane >> 4, l16 = lane & 15;
  const int srow = lane >> 3;
  const int scol = ((lane & 7) ^ srow) * 8;

  floatx4 acc[4][4] = {};

  for (int k0 = 0; k0 < ISH; k0 += BK) {
#pragma unroll
    for (int s = 0; s < 4; s++) {
      int rb = (wave * 4 + s) * 8;
      gload16(Hsh + (size_t)(tm0 + rb + srow) * ISH + k0 + scol, As + rb * BK);
      gload16(SdT + (size_t)(tn0 + rb + srow) * ISH + k0 + scol, Bs + rb * BK);
    }
    __syncthreads();
#pragma unroll
    for (int ks = 0; ks < BK; ks += 32) {
      short8 af[4], bfr[4];
#pragma unroll
      for (int f = 0; f < 4; f++) {
        int ra = wm * 64 + f * 16 + l16;
        int rb2 = wn * 64 + f * 16 + l16;
        af[f] = *(const short8*)(As + ra * BK + ((((ks >> 3) + quad) ^ (ra & 7)) << 3));
        bfr[f] = *(const short8*)(Bs + rb2 * BK + ((((ks >> 3) + quad) ^ (rb2 & 7)) << 3));
      }
#pragma unroll
      for (int fm = 0; fm < 4; fm++)
#pragma unroll
        for (int fn = 0; fn < 4; fn++)
          acc[fm][fn] = mfma16(af[fm], bfr[fn], acc[fm][fn]);
    }
    __syncthreads();
  }
#pragma unroll
  for (int fm = 0; fm < 4; fm++)
#pragma unroll
    for (int reg = 0; reg < 4; reg++) {
      int r = tm0 + wm * 64 + fm * 16 + quad * 4 + reg;
      float gt = sgate[r];
#pragma unroll
      for (int fn = 0; fn < 4; fn++) {
        int c = tn0 + wn * 64 + fn * 16 + l16;
        out[(size_t)r * DDIM + c] = gt * acc[fm][fn][reg];
      }
    }
}

// Expert down proj: out[tok] += w_pair * (Hp @ ed[e]) via atomics. Sequential A.
__global__ __launch_bounds__(256, 2) void k_down_expert(
    const unsigned short* __restrict__ Hp,   // [PADTOT][1024]
    const unsigned short* __restrict__ EdT,  // [E][1024][1024]
    const int* __restrict__ pseg,
    const int* __restrict__ rcnt,
    const int* __restrict__ ptok,
    const float* __restrict__ pw,
    float* __restrict__ out)
{
  const int m0 = blockIdx.x * 128;
  if (m0 >= pseg[NEXP]) return;
  int e = 0;
#pragma unroll
  for (int j = 1; j < NEXP; j++) if (m0 >= pseg[j]) e = j;
  const int sbase = pseg[e];
  const int cnt = rcnt[e];

  __shared__ __align__(16) unsigned short As[128 * BK];
  __shared__ __align__(16) unsigned short Bs[128 * BK];

  const int tn0 = blockIdx.y * 128;
  const int tid = threadIdx.x;
  const int wave = tid >> 6, lane = tid & 63;
  const int wm = wave & 1, wn = wave >> 1;
  const int quad = lane >> 4, l16 = lane & 15;
  const int srow = lane >> 3;
  const int scol = ((lane & 7) ^ srow) * 8;

  const unsigned short* B = EdT + (size_t)e * IMOE * DDIM;

  floatx4 acc[4][4] = {};

  for (int k0 = 0; k0 < IMOE; k0 += BK) {
#pragma unroll
    for (int s = 0; s < 4; s++) {
      int rb = (wave * 4 + s) * 8;
      gload16(Hp + (size_t)(m0 + rb + srow) * IMOE + k0 + scol, As + rb * BK);
      gload16(B + (size_t)(tn0 + rb + srow) * IMOE + k0 + scol, Bs + rb * BK);
    }
    __syncthreads();
#pragma unroll
    for (int ks = 0; ks < BK; ks += 32) {
      short8 af[4], bfr[4];
#pragma unroll
      for (int f = 0; f < 4; f++) {
        int ra = wm * 64 + f * 16 + l16;
        int rb2 = wn * 64 + f * 16 + l16;
        af[f] = *(const short8*)(As + ra * BK + ((((ks >> 3) + quad) ^ (ra & 7)) << 3));
        bfr[f] = *(const short8*)(Bs + rb2 * BK + ((((ks >> 3) + quad) ^ (rb2 & 7)) << 3));
      }
#pragma unroll
      for (int fm = 0; fm < 4; fm++)
#pragma unroll
        for (int fn = 0; fn < 4; fn++)
          acc[fm][fn] = mfma16(af[fm], bfr[fn], acc[fm][fn]);
    }
    __syncthreads();
  }
#pragma unroll
  for (int fm = 0; fm < 4; fm++)
#pragma unroll
    for (int reg = 0; reg < 4; reg++) {
      int grow = m0 + wm * 64 + fm * 16 + quad * 4 + reg;
      if (grow - sbase < cnt) {
        int t = ptok[grow];
        float w = pw[grow];
#pragma unroll
        for (int fn = 0; fn < 4; fn++) {
          int c = tn0 + wn * 64 + fn * 16 + l16;
          atomicAdd(&out[(size_t)t * DDIM + c], w * acc[fm][fn][reg]);
        }
      }
    }
}

// ---------------- launch ----------------

extern "C" void kernel_launch(void* const* d_in, const int* in_sizes, int n_in,
                              void* d_out, int out_size, void* d_ws, size_t ws_size,
                              hipStream_t stream) {
  const float* x   = (const float*)d_in[0];
  const float* gw  = (const float*)d_in[1];
  const float* eg  = (const float*)d_in[2];
  const float* eu  = (const float*)d_in[3];
  const float* ed  = (const float*)d_in[4];
  const float* sg  = (const float*)d_in[5];
  const float* su  = (const float*)d_in[6];
  const float* sd  = (const float*)d_in[7];
  const float* sgw = (const float*)d_in[8];

  float* out    = (float*)d_out;                 // [8192][1024]
  float* logits = out + (size_t)T_TOK * DDIM;    // [8192][8]

  char* ws = (char*)d_ws;
  unsigned short* xb   = (unsigned short*)(ws + 0);            // 16 MB
  unsigned short* egT  = (unsigned short*)(ws + 16777216);     // 16 MB
  unsigned short* euT  = (unsigned short*)(ws + 33554432);     // 16 MB
  unsigned short* edT  = (unsigned short*)(ws + 50331648);     // 16 MB
  unsigned short* sgT  = (unsigned short*)(ws + 67108864);     // 8 MB
  unsigned short* suT  = (unsigned short*)(ws + 75497472);     // 8 MB
  unsigned short* sdT  = (unsigned short*)(ws + 83886080);     // 8 MB
  // hsh (64 MB) and xg (35.7 MB) share this region: xg is dead before
  // k_gu_shared writes hsh (stream-ordered).
  unsigned short* hsh  = (unsigned short*)(ws + 92274688);     // 64 MB
  unsigned short* xg   = (unsigned short*)(ws + 92274688);     // 35.7 MB (union)
  unsigned short* hp   = (unsigned short*)(ws + 159383552);    // 35.7 MB
  int*   topi      = (int*)  (ws + 195035136);   // 16384 ints
  float* topw      = (float*)(ws + 195100672);   // 16384 floats
  float* sgate     = (float*)(ws + 195166208);   // 8192 floats
  int*   ptok      = (int*)  (ws + 195198976);   // PADTOT ints
  float* pw        = (float*)(ws + 195268608);   // PADTOT floats
  int*   blockhist = (int*)  (ws + 195338240);   // 64*8 ints
  int*   blockbase = (int*)  (ws + 195340288);   // 64*8 ints
  int*   pseg      = (int*)  (ws + 195342336);   // 9 ints
  int*   rcnt      = (int*)  (ws + 195342400);   // 8 ints

  k_cast<<<8192, 256, 0, stream>>>(x, xb, T_TOK * DDIM);
  k_transpose_cast<<<dim3(32, 32, 8), dim3(32, 8), 0, stream>>>(eg, egT, DDIM, IMOE);
  k_transpose_cast<<<dim3(32, 32, 8), dim3(32, 8), 0, stream>>>(eu, euT, DDIM, IMOE);
  k_transpose_cast<<<dim3(32, 32, 8), dim3(32, 8), 0, stream>>>(ed, edT, IMOE, DDIM);
  k_transpose_cast<<<dim3(128, 32, 1), dim3(32, 8), 0, stream>>>(sg, sgT, DDIM, ISH);
  k_transpose_cast<<<dim3(128, 32, 1), dim3(32, 8), 0, stream>>>(su, suT, DDIM, ISH);
  k_transpose_cast<<<dim3(32, 128, 1), dim3(32, 8), 0, stream>>>(sd, sdT, ISH, DDIM);

  k_router<<<T_TOK / 4, 256, 0, stream>>>(x, gw, sgw, logits, topi, topw, sgate);
  k_hist<<<64, 256, 0, stream>>>(topi, blockhist);
  k_offsets<<<1, 64, 0, stream>>>(blockhist, pseg, rcnt, blockbase);
  k_scatter<<<64, 256, 0, stream>>>(topi, topw, blockbase, ptok, pw);
  k_gather<<<PADTOT / 2, 256, 0, stream>>>(xb, ptok, xg);

  k_gu_expert<<<dim3(PADTOT / 128, 16), 256, 0, stream>>>(xg, egT, euT, pseg, hp);
  k_gu_shared<<<dim3(64, 64), 256, 0, stream>>>(xb, sgT, suT, hsh);
  k_down_shared<<<dim3(64, 8), 256, 0, stream>>>(hsh, sdT, sgate, out);
  k_down_expert<<<dim3(PADTOT / 128, 8), 256, 0, stream>>>(hp, edT, pseg, rcnt, ptok, pw, out);

  (void)in_sizes; (void)n_in; (void)out_size; (void)ws_size;
}

// Round 5
// 681.568 us; speedup vs baseline: 1.5215x; 1.0145x over previous
//
#include <hip/hip_runtime.h>
#include <hip/hip_bf16.h>
#include <stdint.h>

#define T_TOK 8192
#define DDIM 1024
#define NEXP 8
#define IMOE 1024
#define ISH 4096
#define BK 64
#define PADTOT 17408  // 16384 pairs + 8*128 max padding

typedef __attribute__((ext_vector_type(8))) short short8;
typedef __attribute__((ext_vector_type(8))) __bf16 bf16x8;
typedef __attribute__((ext_vector_type(4))) float floatx4;

// round-to-nearest-even fp32 -> bf16 bits
__device__ __forceinline__ unsigned short f2bf(float f) {
  union { float f; unsigned u; } v; v.f = f;
  unsigned r = v.u + 0x7fffu + ((v.u >> 16) & 1u);
  return (unsigned short)(r >> 16);
}

__device__ __forceinline__ floatx4 mfma16(short8 a, short8 b, floatx4 c) {
  return __builtin_amdgcn_mfma_f32_16x16x32_bf16(
      __builtin_bit_cast(bf16x8, a), __builtin_bit_cast(bf16x8, b), c, 0, 0, 0);
}

// async global->LDS, 16B per lane; LDS base must be wave-uniform
__device__ __forceinline__ void gload16(const void* g, void* l) {
  __builtin_amdgcn_global_load_lds((const __attribute__((address_space(1))) void*)g,
                                   (__attribute__((address_space(3))) void*)l, 16, 0, 0);
}

// XOR swizzle: LDS 16B-block b of row r holds global block (b ^ (r&7)).
// Breaks the 16-way bank-group conflict of the BK=64 row stride (128B == 32 banks).

// ---------------- conversion kernels ----------------

__global__ void k_cast(const float* __restrict__ src, unsigned short* __restrict__ dst, int n) {
  int i = (blockIdx.x * blockDim.x + threadIdx.x) * 4;
  if (i < n) {
    float4 v = *(const float4*)(src + i);
    ushort4 o;
    o.x = f2bf(v.x); o.y = f2bf(v.y); o.z = f2bf(v.z); o.w = f2bf(v.w);
    *(ushort4*)(dst + i) = o;
  }
}

// src [batch][R][C] f32 -> dst [batch][C][R] bf16  (B^T layout for GEMM)
__global__ void k_transpose_cast(const float* __restrict__ src, unsigned short* __restrict__ dst,
                                 int R, int C) {
  __shared__ float tile[32][33];
  int b = blockIdx.z;
  int c0 = blockIdx.x * 32, r0 = blockIdx.y * 32;
  const float* s = src + (size_t)b * R * C;
  unsigned short* d = dst + (size_t)b * R * C;
  int tx = threadIdx.x, ty = threadIdx.y;  // 32 x 8
#pragma unroll
  for (int j = 0; j < 32; j += 8)
    tile[ty + j][tx] = s[(size_t)(r0 + ty + j) * C + c0 + tx];
  __syncthreads();
#pragma unroll
  for (int j = 0; j < 32; j += 8)
    d[(size_t)(c0 + ty + j) * R + r0 + tx] = f2bf(tile[tx][ty + j]);
}

// ---------------- router (no global atomics) ----------------

__global__ void k_router(const float* __restrict__ x, const float* __restrict__ gw,
                         const float* __restrict__ sgw, float* __restrict__ logits_out,
                         int* __restrict__ topi, float* __restrict__ topw,
                         float* __restrict__ sgate) {
  int wave = threadIdx.x >> 6;
  int lane = threadIdx.x & 63;
  int t = blockIdx.x * 4 + wave;
  const float* xr = x + (size_t)t * DDIM;
  float acc[9];
#pragma unroll
  for (int j = 0; j < 9; j++) acc[j] = 0.f;
  for (int d = lane; d < DDIM; d += 64) {
    float xv = xr[d];
    const float* g = gw + d * 8;
    float4 g0 = *(const float4*)g;
    float4 g1 = *(const float4*)(g + 4);
    acc[0] += xv * g0.x; acc[1] += xv * g0.y; acc[2] += xv * g0.z; acc[3] += xv * g0.w;
    acc[4] += xv * g1.x; acc[5] += xv * g1.y; acc[6] += xv * g1.z; acc[7] += xv * g1.w;
    acc[8] += xv * sgw[d];
  }
#pragma unroll
  for (int off = 32; off > 0; off >>= 1) {
#pragma unroll
    for (int j = 0; j < 9; j++) acc[j] += __shfl_xor(acc[j], off);
  }
  if (lane == 0) {
#pragma unroll
    for (int j = 0; j < 8; j++) logits_out[t * 8 + j] = acc[j];
    int i0 = 0;
#pragma unroll
    for (int j = 1; j < 8; j++) if (acc[j] > acc[i0]) i0 = j;
    int i1 = -1;
#pragma unroll
    for (int j = 0; j < 8; j++) {
      if (j == i0) continue;
      if (i1 < 0 || acc[j] > acc[i1]) i1 = j;
    }
    float e1 = expf(acc[i1] - acc[i0]);  // e0 = 1
    float inv = 1.f / (1.f + e1);
    topi[t * 2] = i0; topi[t * 2 + 1] = i1;
    topw[t * 2] = inv; topw[t * 2 + 1] = e1 * inv;
    sgate[t] = 1.f / (1.f + expf(-acc[8]));
  }
}

// Counting sort pass 1: per-block expert histogram (LDS atomics only).
__global__ void k_hist(const int* __restrict__ topi, int* __restrict__ blockhist) {
  __shared__ int h[NEXP];
  if (threadIdx.x < NEXP) h[threadIdx.x] = 0;
  __syncthreads();
  int i = blockIdx.x * 256 + threadIdx.x;  // pair index
  atomicAdd(&h[topi[i]], 1);
  __syncthreads();
  if (threadIdx.x < NEXP) blockhist[blockIdx.x * NEXP + threadIdx.x] = h[threadIdx.x];
}

// Pass 2: padded segment offsets (multiples of 128) + per-block bases + real counts.
__global__ void k_offsets(const int* __restrict__ blockhist, int* __restrict__ pseg,
                          int* __restrict__ rcnt, int* __restrict__ blockbase) {
  if (threadIdx.x == 0) {
    int tot[NEXP];
#pragma unroll
    for (int e = 0; e < NEXP; e++) tot[e] = 0;
    for (int b = 0; b < 64; b++)
      for (int e = 0; e < NEXP; e++) {
        blockbase[b * NEXP + e] = tot[e];
        tot[e] += blockhist[b * NEXP + e];
      }
    int s = 0;
    for (int e = 0; e < NEXP; e++) {
      rcnt[e] = tot[e];
      pseg[e] = s;
      s += (tot[e] + 127) & ~127;  // pad each segment to 128
    }
    pseg[NEXP] = s;
    for (int b = 0; b < 64; b++)
      for (int e = 0; e < NEXP; e++) blockbase[b * NEXP + e] += pseg[e];
  }
}

// Pass 3: scatter with per-block LDS cursors (no global atomics).
__global__ void k_scatter(const int* __restrict__ topi, const float* __restrict__ topw,
                          const int* __restrict__ blockbase,
                          int* __restrict__ ptok, float* __restrict__ pw) {
  __shared__ int cur[NEXP];
  if (threadIdx.x < NEXP) cur[threadIdx.x] = blockbase[blockIdx.x * NEXP + threadIdx.x];
  __syncthreads();
  int i = blockIdx.x * 256 + threadIdx.x;  // pair index
  int e = topi[i];
  int pos = atomicAdd(&cur[e], 1);
  ptok[pos] = i >> 1;
  pw[pos] = topw[i];
}

// Pass 4: physically gather X rows into contiguous pair-slot order (bf16 copy).
// Pad / unwritten slots (ptok poisoned) -> zero rows.
__global__ void k_gather(const unsigned short* __restrict__ xb, const int* __restrict__ ptok,
                         unsigned short* __restrict__ xg) {
  int row = blockIdx.x * 2 + (threadIdx.x >> 7);
  int col = (threadIdx.x & 127) * 8;
  int tok = ptok[row];
  uint4 v = make_uint4(0, 0, 0, 0);
  if (tok >= 0 && tok < T_TOK) v = *(const uint4*)(xb + (size_t)tok * DDIM + col);
  *(uint4*)(xg + (size_t)row * DDIM + col) = v;
}

// ---------------- GEMM kernels (MFMA bf16 16x16x32, XOR-swizzled LDS) ----------------
// 32 KB LDS/block, VGPR<=128 -> 4 blocks/CU at __launch_bounds__(256,4).
// Fused gate/up + SiLU, shared expert: C tile 128(M) x 64(N), dual-B accs.
__global__ __launch_bounds__(256, 4) void k_gu_shared(
    const unsigned short* __restrict__ Xb,   // [8192][1024]
    const unsigned short* __restrict__ BgT,  // [4096][1024]
    const unsigned short* __restrict__ BuT,  // [4096][1024]
    unsigned short* __restrict__ H)          // [8192][4096]
{
  __shared__ __align__(16) unsigned short As[128 * BK];
  __shared__ __align__(16) unsigned short Bgs[64 * BK];
  __shared__ __align__(16) unsigned short Bus[64 * BK];

  const int tm0 = blockIdx.x * 128;
  const int tn0 = blockIdx.y * 64;
  const int tid = threadIdx.x;
  const int wave = tid >> 6, lane = tid & 63;
  const int wm = wave & 1, wn = wave >> 1;
  const int quad = lane >> 4, l16 = lane & 15;
  const int srow = lane >> 3;                        // 8 lanes per 64-elem row
  const int scol = ((lane & 7) ^ srow) * 8;          // swizzled global col block

  floatx4 accg[4][2] = {};
  floatx4 accu[4][2] = {};

  for (int k0 = 0; k0 < DDIM; k0 += BK) {
#pragma unroll
    for (int s = 0; s < 4; s++) {
      int rb = (wave * 4 + s) * 8;
      gload16(Xb + (size_t)(tm0 + rb + srow) * DDIM + k0 + scol, As + rb * BK);
    }
#pragma unroll
    for (int s = 0; s < 2; s++) {
      int rb = (wave * 2 + s) * 8;
      gload16(BgT + (size_t)(tn0 + rb + srow) * DDIM + k0 + scol, Bgs + rb * BK);
      gload16(BuT + (size_t)(tn0 + rb + srow) * DDIM + k0 + scol, Bus + rb * BK);
    }
    __syncthreads();
#pragma unroll
    for (int ks = 0; ks < BK; ks += 32) {
      short8 af[4], bg[2], bu[2];
#pragma unroll
      for (int f = 0; f < 4; f++) {
        int r = wm * 64 + f * 16 + l16;
        af[f] = *(const short8*)(As + r * BK + ((((ks >> 3) + quad) ^ (r & 7)) << 3));
      }
#pragma unroll
      for (int f = 0; f < 2; f++) {
        int r = wn * 32 + f * 16 + l16;
        int off = r * BK + ((((ks >> 3) + quad) ^ (r & 7)) << 3);
        bg[f] = *(const short8*)(Bgs + off);
        bu[f] = *(const short8*)(Bus + off);
      }
#pragma unroll
      for (int fm = 0; fm < 4; fm++)
#pragma unroll
        for (int fn = 0; fn < 2; fn++) {
          accg[fm][fn] = mfma16(af[fm], bg[fn], accg[fm][fn]);
          accu[fm][fn] = mfma16(af[fm], bu[fn], accu[fm][fn]);
        }
    }
    __syncthreads();
  }
#pragma unroll
  for (int fm = 0; fm < 4; fm++)
#pragma unroll
    for (int reg = 0; reg < 4; reg++) {
      int r = tm0 + wm * 64 + fm * 16 + quad * 4 + reg;
#pragma unroll
      for (int fn = 0; fn < 2; fn++) {
        int c = tn0 + wn * 32 + fn * 16 + l16;
        float g = accg[fm][fn][reg];
        float u = accu[fm][fn][reg];
        float h = (g / (1.f + __expf(-g))) * u;
        H[(size_t)r * ISH + c] = f2bf(h);
      }
    }
}

// Fused gate/up + SiLU for routed experts — sequential A from gathered Xg.
__global__ __launch_bounds__(256, 4) void k_gu_expert(
    const unsigned short* __restrict__ Xg,   // [PADTOT][1024] gathered
    const unsigned short* __restrict__ EgT,  // [E][1024][1024]
    const unsigned short* __restrict__ EuT,
    const int* __restrict__ pseg,
    unsigned short* __restrict__ Hp)         // [PADTOT][1024] by pair slot
{
  const int m0 = blockIdx.x * 128;
  if (m0 >= pseg[NEXP]) return;
  int e = 0;
#pragma unroll
  for (int j = 1; j < NEXP; j++) if (m0 >= pseg[j]) e = j;

  __shared__ __align__(16) unsigned short As[128 * BK];
  __shared__ __align__(16) unsigned short Bgs[64 * BK];
  __shared__ __align__(16) unsigned short Bus[64 * BK];

  const int tn0 = blockIdx.y * 64;
  const int tid = threadIdx.x;
  const int wave = tid >> 6, lane = tid & 63;
  const int wm = wave & 1, wn = wave >> 1;
  const int quad = lane >> 4, l16 = lane & 15;
  const int srow = lane >> 3;
  const int scol = ((lane & 7) ^ srow) * 8;

  const unsigned short* Bg = EgT + (size_t)e * IMOE * DDIM;
  const unsigned short* Bu = EuT + (size_t)e * IMOE * DDIM;

  floatx4 accg[4][2] = {};
  floatx4 accu[4][2] = {};

  for (int k0 = 0; k0 < DDIM; k0 += BK) {
#pragma unroll
    for (int s = 0; s < 4; s++) {
      int rb = (wave * 4 + s) * 8;
      gload16(Xg + (size_t)(m0 + rb + srow) * DDIM + k0 + scol, As + rb * BK);
    }
#pragma unroll
    for (int s = 0; s < 2; s++) {
      int rb = (wave * 2 + s) * 8;
      gload16(Bg + (size_t)(tn0 + rb + srow) * DDIM + k0 + scol, Bgs + rb * BK);
      gload16(Bu + (size_t)(tn0 + rb + srow) * DDIM + k0 + scol, Bus + rb * BK);
    }
    __syncthreads();
#pragma unroll
    for (int ks = 0; ks < BK; ks += 32) {
      short8 af[4], bg[2], bu[2];
#pragma unroll
      for (int f = 0; f < 4; f++) {
        int r = wm * 64 + f * 16 + l16;
        af[f] = *(const short8*)(As + r * BK + ((((ks >> 3) + quad) ^ (r & 7)) << 3));
      }
#pragma unroll
      for (int f = 0; f < 2; f++) {
        int r = wn * 32 + f * 16 + l16;
        int off = r * BK + ((((ks >> 3) + quad) ^ (r & 7)) << 3);
        bg[f] = *(const short8*)(Bgs + off);
        bu[f] = *(const short8*)(Bus + off);
      }
#pragma unroll
      for (int fm = 0; fm < 4; fm++)
#pragma unroll
        for (int fn = 0; fn < 2; fn++) {
          accg[fm][fn] = mfma16(af[fm], bg[fn], accg[fm][fn]);
          accu[fm][fn] = mfma16(af[fm], bu[fn], accu[fm][fn]);
        }
    }
    __syncthreads();
  }
#pragma unroll
  for (int fm = 0; fm < 4; fm++)
#pragma unroll
    for (int reg = 0; reg < 4; reg++) {
      int r = m0 + wm * 64 + fm * 16 + quad * 4 + reg;
#pragma unroll
      for (int fn = 0; fn < 2; fn++) {
        int c = tn0 + wn * 32 + fn * 16 + l16;
        float g = accg[fm][fn][reg];
        float u = accu[fm][fn][reg];
        Hp[(size_t)r * IMOE + c] = f2bf((g / (1.f + __expf(-g))) * u);
      }
    }
}

// Shared-expert down proj: out = sigmoid_gate[t] * (Hsh @ sd). Writes full out.
__global__ __launch_bounds__(256, 4) void k_down_shared(
    const unsigned short* __restrict__ Hsh,  // [8192][4096]
    const unsigned short* __restrict__ SdT,  // [1024][4096]
    const float* __restrict__ sgate,
    float* __restrict__ out)                 // [8192][1024]
{
  __shared__ __align__(16) unsigned short As[128 * BK];
  __shared__ __align__(16) unsigned short Bs[128 * BK];

  const int tm0 = blockIdx.x * 128;
  const int tn0 = blockIdx.y * 128;
  const int tid = threadIdx.x;
  const int wave = tid >> 6, lane = tid & 63;
  const int wm = wave & 1, wn = wave >> 1;
  const int quad = lane >> 4, l16 = lane & 15;
  const int srow = lane >> 3;
  const int scol = ((lane & 7) ^ srow) * 8;

  floatx4 acc[4][4] = {};

  for (int k0 = 0; k0 < ISH; k0 += BK) {
#pragma unroll
    for (int s = 0; s < 4; s++) {
      int rb = (wave * 4 + s) * 8;
      gload16(Hsh + (size_t)(tm0 + rb + srow) * ISH + k0 + scol, As + rb * BK);
      gload16(SdT + (size_t)(tn0 + rb + srow) * ISH + k0 + scol, Bs + rb * BK);
    }
    __syncthreads();
#pragma unroll
    for (int ks = 0; ks < BK; ks += 32) {
      short8 af[4], bfr[4];
#pragma unroll
      for (int f = 0; f < 4; f++) {
        int ra = wm * 64 + f * 16 + l16;
        int rb2 = wn * 64 + f * 16 + l16;
        af[f] = *(const short8*)(As + ra * BK + ((((ks >> 3) + quad) ^ (ra & 7)) << 3));
        bfr[f] = *(const short8*)(Bs + rb2 * BK + ((((ks >> 3) + quad) ^ (rb2 & 7)) << 3));
      }
#pragma unroll
      for (int fm = 0; fm < 4; fm++)
#pragma unroll
        for (int fn = 0; fn < 4; fn++)
          acc[fm][fn] = mfma16(af[fm], bfr[fn], acc[fm][fn]);
    }
    __syncthreads();
  }
#pragma unroll
  for (int fm = 0; fm < 4; fm++)
#pragma unroll
    for (int reg = 0; reg < 4; reg++) {
      int r = tm0 + wm * 64 + fm * 16 + quad * 4 + reg;
      float gt = sgate[r];
#pragma unroll
      for (int fn = 0; fn < 4; fn++) {
        int c = tn0 + wn * 64 + fn * 16 + l16;
        out[(size_t)r * DDIM + c] = gt * acc[fm][fn][reg];
      }
    }
}

// Expert down proj: out[tok] += w_pair * (Hp @ ed[e]) via atomics. Sequential A.
__global__ __launch_bounds__(256, 4) void k_down_expert(
    const unsigned short* __restrict__ Hp,   // [PADTOT][1024]
    const unsigned short* __restrict__ EdT,  // [E][1024][1024]
    const int* __restrict__ pseg,
    const int* __restrict__ rcnt,
    const int* __restrict__ ptok,
    const float* __restrict__ pw,
    float* __restrict__ out)
{
  const int m0 = blockIdx.x * 128;
  if (m0 >= pseg[NEXP]) return;
  int e = 0;
#pragma unroll
  for (int j = 1; j < NEXP; j++) if (m0 >= pseg[j]) e = j;
  const int sbase = pseg[e];
  const int cnt = rcnt[e];

  __shared__ __align__(16) unsigned short As[128 * BK];
  __shared__ __align__(16) unsigned short Bs[128 * BK];

  const int tn0 = blockIdx.y * 128;
  const int tid = threadIdx.x;
  const int wave = tid >> 6, lane = tid & 63;
  const int wm = wave & 1, wn = wave >> 1;
  const int quad = lane >> 4, l16 = lane & 15;
  const int srow = lane >> 3;
  const int scol = ((lane & 7) ^ srow) * 8;

  const unsigned short* B = EdT + (size_t)e * IMOE * DDIM;

  floatx4 acc[4][4] = {};

  for (int k0 = 0; k0 < IMOE; k0 += BK) {
#pragma unroll
    for (int s = 0; s < 4; s++) {
      int rb = (wave * 4 + s) * 8;
      gload16(Hp + (size_t)(m0 + rb + srow) * IMOE + k0 + scol, As + rb * BK);
      gload16(B + (size_t)(tn0 + rb + srow) * IMOE + k0 + scol, Bs + rb * BK);
    }
    __syncthreads();
#pragma unroll
    for (int ks = 0; ks < BK; ks += 32) {
      short8 af[4], bfr[4];
#pragma unroll
      for (int f = 0; f < 4; f++) {
        int ra = wm * 64 + f * 16 + l16;
        int rb2 = wn * 64 + f * 16 + l16;
        af[f] = *(const short8*)(As + ra * BK + ((((ks >> 3) + quad) ^ (ra & 7)) << 3));
        bfr[f] = *(const short8*)(Bs + rb2 * BK + ((((ks >> 3) + quad) ^ (rb2 & 7)) << 3));
      }
#pragma unroll
      for (int fm = 0; fm < 4; fm++)
#pragma unroll
        for (int fn = 0; fn < 4; fn++)
          acc[fm][fn] = mfma16(af[fm], bfr[fn], acc[fm][fn]);
    }
    __syncthreads();
  }
#pragma unroll
  for (int fm = 0; fm < 4; fm++)
#pragma unroll
    for (int reg = 0; reg < 4; reg++) {
      int grow = m0 + wm * 64 + fm * 16 + quad * 4 + reg;
      if (grow - sbase < cnt) {
        int t = ptok[grow];
        float w = pw[grow];
#pragma unroll
        for (int fn = 0; fn < 4; fn++) {
          int c = tn0 + wn * 64 + fn * 16 + l16;
          atomicAdd(&out[(size_t)t * DDIM + c], w * acc[fm][fn][reg]);
        }
      }
    }
}

// ---------------- launch ----------------

extern "C" void kernel_launch(void* const* d_in, const int* in_sizes, int n_in,
                              void* d_out, int out_size, void* d_ws, size_t ws_size,
                              hipStream_t stream) {
  const float* x   = (const float*)d_in[0];
  const float* gw  = (const float*)d_in[1];
  const float* eg  = (const float*)d_in[2];
  const float* eu  = (const float*)d_in[3];
  const float* ed  = (const float*)d_in[4];
  const float* sg  = (const float*)d_in[5];
  const float* su  = (const float*)d_in[6];
  const float* sd  = (const float*)d_in[7];
  const float* sgw = (const float*)d_in[8];

  float* out    = (float*)d_out;                 // [8192][1024]
  float* logits = out + (size_t)T_TOK * DDIM;    // [8192][8]

  char* ws = (char*)d_ws;
  unsigned short* xb   = (unsigned short*)(ws + 0);            // 16 MB
  unsigned short* egT  = (unsigned short*)(ws + 16777216);     // 16 MB
  unsigned short* euT  = (unsigned short*)(ws + 33554432);     // 16 MB
  unsigned short* edT  = (unsigned short*)(ws + 50331648);     // 16 MB
  unsigned short* sgT  = (unsigned short*)(ws + 67108864);     // 8 MB
  unsigned short* suT  = (unsigned short*)(ws + 75497472);     // 8 MB
  unsigned short* sdT  = (unsigned short*)(ws + 83886080);     // 8 MB
  // hsh (64 MB) and xg (35.7 MB) share this region: xg is dead before
  // k_gu_shared writes hsh (stream-ordered).
  unsigned short* hsh  = (unsigned short*)(ws + 92274688);     // 64 MB
  unsigned short* xg   = (unsigned short*)(ws + 92274688);     // 35.7 MB (union)
  unsigned short* hp   = (unsigned short*)(ws + 159383552);    // 35.7 MB
  int*   topi      = (int*)  (ws + 195035136);   // 16384 ints
  float* topw      = (float*)(ws + 195100672);   // 16384 floats
  float* sgate     = (float*)(ws + 195166208);   // 8192 floats
  int*   ptok      = (int*)  (ws + 195198976);   // PADTOT ints
  float* pw        = (float*)(ws + 195268608);   // PADTOT floats
  int*   blockhist = (int*)  (ws + 195338240);   // 64*8 ints
  int*   blockbase = (int*)  (ws + 195340288);   // 64*8 ints
  int*   pseg      = (int*)  (ws + 195342336);   // 9 ints
  int*   rcnt      = (int*)  (ws + 195342400);   // 8 ints

  k_cast<<<8192, 256, 0, stream>>>(x, xb, T_TOK * DDIM);
  k_transpose_cast<<<dim3(32, 32, 8), dim3(32, 8), 0, stream>>>(eg, egT, DDIM, IMOE);
  k_transpose_cast<<<dim3(32, 32, 8), dim3(32, 8), 0, stream>>>(eu, euT, DDIM, IMOE);
  k_transpose_cast<<<dim3(32, 32, 8), dim3(32, 8), 0, stream>>>(ed, edT, IMOE, DDIM);
  k_transpose_cast<<<dim3(128, 32, 1), dim3(32, 8), 0, stream>>>(sg, sgT, DDIM, ISH);
  k_transpose_cast<<<dim3(128, 32, 1), dim3(32, 8), 0, stream>>>(su, suT, DDIM, ISH);
  k_transpose_cast<<<dim3(32, 128, 1), dim3(32, 8), 0, stream>>>(sd, sdT, ISH, DDIM);

  k_router<<<T_TOK / 4, 256, 0, stream>>>(x, gw, sgw, logits, topi, topw, sgate);
  k_hist<<<64, 256, 0, stream>>>(topi, blockhist);
  k_offsets<<<1, 64, 0, stream>>>(blockhist, pseg, rcnt, blockbase);
  k_scatter<<<64, 256, 0, stream>>>(topi, topw, blockbase, ptok, pw);
  k_gather<<<PADTOT / 2, 256, 0, stream>>>(xb, ptok, xg);

  k_gu_expert<<<dim3(PADTOT / 128, 16), 256, 0, stream>>>(xg, egT, euT, pseg, hp);
  k_gu_shared<<<dim3(64, 64), 256, 0, stream>>>(xb, sgT, suT, hsh);
  k_down_shared<<<dim3(64, 8), 256, 0, stream>>>(hsh, sdT, sgate, out);
  k_down_expert<<<dim3(PADTOT / 128, 8), 256, 0, stream>>>(hp, edT, pseg, rcnt, ptok, pw, out);

  (void)in_sizes; (void)n_in; (void)out_size; (void)ws_size;
}